// Round 5
// baseline (4705.362 us; speedup 1.0000x reference)
//
#include <hip/hip_runtime.h>
#include <hip/hip_bf16.h>
#include <math.h>

#define VDIM 128
#define HDIM 512
#define BATCH 512
#define RPB 4                  // batch rows per scan block
#define NBLK (BATCH / RPB)     // 128 scan blocks
#define NT 512                 // scan threads (8 waves)
#define LN_EPS 1e-5f
#define PF 4                   // weight prefetch depth (float4-pairs in flight)

#define FNT 256                // fnet threads (4 waves)
#define FROWS 16               // fnet rows per tile
#define FRG (BATCH / FROWS)    // 32 row groups
#define FGRID (VDIM * FRG)     // 4096 fnet blocks

// ---------- float4 helpers ----------
__device__ __forceinline__ float4 f4zero() { return make_float4(0.f, 0.f, 0.f, 0.f); }
__device__ __forceinline__ float4 f4add(float4 a, float4 b) {
    return make_float4(a.x + b.x, a.y + b.y, a.z + b.z, a.w + b.w);
}
__device__ __forceinline__ float4 f4fma(float4 a, float s, float4 c) {
    return make_float4(fmaf(a.x, s, c.x), fmaf(a.y, s, c.y),
                       fmaf(a.z, s, c.z), fmaf(a.w, s, c.w));
}
__device__ __forceinline__ float4 f4scale(float4 a, float s) {
    return make_float4(a.x * s, a.y * s, a.z * s, a.w * s);
}
__device__ __forceinline__ float4 f4sub(float4 a, float4 b) {
    return make_float4(a.x - b.x, a.y - b.y, a.z - b.z, a.w - b.w);
}
__device__ __forceinline__ float f4get(float4 v, int r) {
    return r == 0 ? v.x : r == 1 ? v.y : r == 2 ? v.z : v.w;
}

struct Params {
    const float *u;
    const float *q_w1, *q_b1, *q_g1, *q_be1;
    const float *q_w2, *q_b2, *q_g2, *q_be2;
    const float *q_w3, *q_b3, *q_g3, *q_be3;
    const float *q_W, *q_bias, *q_marg;
    const float *f_w1, *f_b1, *f_g1, *f_be1;
    const float *f_w2, *f_b2, *f_g2, *f_be2;
    const float *f_w3, *f_b3, *f_g3, *f_be3;
    const float *f_w4, *f_b4, *J;
    const int *top_order, *pa_mask;
    float *V_out, *lp, *lf, *score, *vs, *loss;
};

// block-wide (512 thr) deterministic float4 allreduce
__device__ __forceinline__ float4 allreduce4(float4 v, float4 *red4, int tid) {
#pragma unroll
    for (int off = 1; off < 64; off <<= 1) {
        v.x += __shfl_xor(v.x, off, 64);
        v.y += __shfl_xor(v.y, off, 64);
        v.z += __shfl_xor(v.z, off, 64);
        v.w += __shfl_xor(v.w, off, 64);
    }
    if ((tid & 63) == 0) red4[tid >> 6] = v;
    __syncthreads();
    float4 s = red4[0];
#pragma unroll
    for (int w = 1; w < 8; ++w) s = f4add(s, red4[w]);
    __syncthreads();
    return s;
}

__device__ __forceinline__ float block_reduce1(float v, float *red, int tid) {
#pragma unroll
    for (int off = 1; off < 64; off <<= 1) v += __shfl_xor(v, off, 64);
    if ((tid & 63) == 0) red[tid >> 6] = v;
    __syncthreads();
    float s = 0.f;
#pragma unroll
    for (int w = 0; w < 8; ++w) s += red[w];
    __syncthreads();
    return s;
}

// ---------------- scan GEMV+LN: 4 rows, 8-way K-split, CPT=8 ----------------
// inAT[k] = float4 of 4 rows' activation at k.  W: [K][HDIM] row-major.
// GEMV: wave ks=tid>>6 owns K-chunk; lane cq=tid&63 owns float4 col-blocks
// {cq, 64+cq}.  Partials: part[j][ks][cq] (conflict-free writes).
// Combine+LN: all 512 threads, thread tid owns column tid.
template <int K>
__device__ __forceinline__ void gemv_ln_scan(const float4 *__restrict__ inAT,
                                             const float *__restrict__ W,
                                             const float *__restrict__ bias,
                                             const float *__restrict__ gam,
                                             const float *__restrict__ bet,
                                             float4 *__restrict__ outAT,
                                             float4 (*partA)[8][64],
                                             float4 (*partB)[8][64],
                                             float4 *red4,
                                             int tid, int ks, int cq) {
    const int kc = K / 8;
    const float4 *inP = inAT + ks * kc;
    const float4 *Wk = (const float4 *)W + (size_t)(ks * kc) * (HDIM / 4) + cq;

    float4 acA0 = f4zero(), acA1 = f4zero(), acA2 = f4zero(), acA3 = f4zero();
    float4 acB0 = f4zero(), acB1 = f4zero(), acB2 = f4zero(), acB3 = f4zero();

    float4 wA[PF], wB[PF];
#pragma unroll
    for (int p = 0; p < PF; ++p) {
        wA[p] = Wk[(size_t)p * (HDIM / 4)];
        wB[p] = Wk[(size_t)p * (HDIM / 4) + 64];
    }
    // main loop: prefetch PF ahead (kc and kc-PF are multiples of PF)
#pragma unroll 4
    for (int k = 0; k < kc - PF; ++k) {
        const int p = k & (PF - 1);
        float4 a = inP[k];                       // LDS b128, wave-uniform broadcast
        float4 cA = wA[p], cB = wB[p];
        wA[p] = Wk[(size_t)(k + PF) * (HDIM / 4)];
        wB[p] = Wk[(size_t)(k + PF) * (HDIM / 4) + 64];
        acA0 = f4fma(a, cA.x, acA0); acA1 = f4fma(a, cA.y, acA1);
        acA2 = f4fma(a, cA.z, acA2); acA3 = f4fma(a, cA.w, acA3);
        acB0 = f4fma(a, cB.x, acB0); acB1 = f4fma(a, cB.y, acB1);
        acB2 = f4fma(a, cB.z, acB2); acB3 = f4fma(a, cB.w, acB3);
    }
#pragma unroll
    for (int k = kc - PF; k < kc; ++k) {
        const int p = k & (PF - 1);
        float4 a = inP[k];
        float4 cA = wA[p], cB = wB[p];
        acA0 = f4fma(a, cA.x, acA0); acA1 = f4fma(a, cA.y, acA1);
        acA2 = f4fma(a, cA.z, acA2); acA3 = f4fma(a, cA.w, acA3);
        acB0 = f4fma(a, cB.x, acB0); acB1 = f4fma(a, cB.y, acB1);
        acB2 = f4fma(a, cB.z, acB2); acB3 = f4fma(a, cB.w, acB3);
    }
    // partials: lane stride 16B -> conflict-free
    partA[0][ks][cq] = acA0; partA[1][ks][cq] = acA1;
    partA[2][ks][cq] = acA2; partA[3][ks][cq] = acA3;
    partB[0][ks][cq] = acB0; partB[1][ks][cq] = acB1;
    partB[2][ks][cq] = acB2; partB[3][ks][cq] = acB3;
    __syncthreads();

    // combine: thread tid owns column c = tid
    const int jj = tid & 3;
    const int cc4 = (tid >> 2) & 63;
    float4 (*part)[8][64] = (tid < 256) ? partA : partB;   // wave-uniform select
    float4 acc = part[jj][0][cc4];
#pragma unroll
    for (int s = 1; s < 8; ++s) acc = f4add(acc, part[jj][s][cc4]);
    float bc = bias[tid];
    acc.x += bc; acc.y += bc; acc.z += bc; acc.w += bc;

    // two-pass LN over 512 columns (acc = 4 rows of col tid)
    const float inv = 1.f / (float)HDIM;
    float4 m4 = f4scale(allreduce4(acc, red4, tid), inv);
    float4 d = f4sub(acc, m4);
    float4 sq = make_float4(d.x * d.x, d.y * d.y, d.z * d.z, d.w * d.w);
    float4 var = f4scale(allreduce4(sq, red4, tid), inv);
    float4 rs;
    rs.x = 1.f / sqrtf(var.x + LN_EPS);
    rs.y = 1.f / sqrtf(var.y + LN_EPS);
    rs.z = 1.f / sqrtf(var.z + LN_EPS);
    rs.w = 1.f / sqrtf(var.w + LN_EPS);
    float gc = gam[tid], ec = bet[tid];
    float4 h;
    h.x = fmaxf(fmaf(d.x * rs.x, gc, ec), 0.f);
    h.y = fmaxf(fmaf(d.y * rs.y, gc, ec), 0.f);
    h.z = fmaxf(fmaf(d.z * rs.z, gc, ec), 0.f);
    h.w = fmaxf(fmaf(d.w * rs.w, gc, ec), 0.f);
    outAT[tid] = h;                                  // lane stride 16B -> conflict-free
    __syncthreads();
}

// ---------------- sequential scan: qtrunk + sampling only ----------------
__global__ __launch_bounds__(NT) void gfn_scan(Params P) {
    __shared__ float4 VT[VDIM];            // V^T: [col] -> 4 rows
    __shared__ float4 VPT[VDIM];
    __shared__ float4 ATa[HDIM];
    __shared__ float4 ATb[HDIM];
    __shared__ float4 partA[4][8][64];     // 16KB
    __shared__ float4 partB[4][8][64];     // 16KB
    __shared__ float4 red4[8];

    const int tid = threadIdx.x;
    const int ks = tid >> 6;               // wave id = K chunk
    const int cq = tid & 63;
    const int row0 = blockIdx.x * RPB;

    if (tid < VDIM) VT[tid] = f4zero();
    __syncthreads();

    for (int i = 0; i < VDIM; ++i) {
        const int node = P.top_order[i];

        float4 ap = f4zero();
        if (tid < VDIM) {
            float mk = (float)P.pa_mask[node * VDIM + tid];
            float4 v = VT[tid];
            float4 vp = f4scale(v, mk);
            VPT[tid] = vp;
            ap = make_float4(fabsf(vp.x), fabsf(vp.y), fabsf(vp.z), fabsf(vp.w));
        }
        float4 asum = allreduce4(ap, red4, tid);   // barriers publish VPT

        gemv_ln_scan<VDIM>(VPT, P.q_w1, P.q_b1, P.q_g1, P.q_be1, ATa, partA, partB, red4, tid, ks, cq);
        gemv_ln_scan<HDIM>(ATa, P.q_w2, P.q_b2, P.q_g2, P.q_be2, ATb, partA, partB, red4, tid, ks, cq);
        gemv_ln_scan<HDIM>(ATb, P.q_w3, P.q_b3, P.q_g3, P.q_be3, ATa, partA, partB, red4, tid, ks, cq);

        // head: x[r] = sum_c h3[r][c] * q_W[node][c]  (all 512 threads, 1 col each)
        float wq = P.q_W[(size_t)node * HDIM + tid];
        float4 xp = f4scale(ATa[tid], wq);
        float4 x4 = allreduce4(xp, red4, tid);

        if (tid < RPB) {
            const int r = tid;
            float asr = f4get(asum, r);
            float xr = f4get(x4, r) + P.q_bias[node];
            float arg = (asr == 0.f) ? P.q_marg[node] : xr;
            float p = 1.f / (1.f + expf(-arg));
            float uv = P.u[i * BATCH + row0 + r];
            bool samp = uv < p;
            float v = samp ? 1.f : -1.f;
            ((float *)&VT[node])[r] = v;
            P.vs[i * BATCH + row0 + r] = v;
            P.lp[i * BATCH + row0 + r] = samp ? logf(p) : log1pf(-p);
        }
        __syncthreads();
    }

    // terminal score
    float4 inner = f4zero();
    if (tid < 128) {
#pragma unroll 4
        for (int ii = 0; ii < VDIM; ++ii)
            inner = f4fma(VT[ii], P.J[(size_t)ii * VDIM + tid], inner);
        float4 vc = VT[tid];
        inner = make_float4(inner.x * vc.x, inner.y * vc.y, inner.z * vc.z, inner.w * vc.w);
    }
    float4 sc4 = allreduce4(inner, red4, tid);
    if (tid < RPB) P.score[row0 + tid] = f4get(sc4, tid);
    if (tid < VDIM) {
        float4 v = VT[tid];
        P.V_out[(size_t)(row0 + 0) * VDIM + tid] = v.x;
        P.V_out[(size_t)(row0 + 1) * VDIM + tid] = v.y;
        P.V_out[(size_t)(row0 + 2) * VDIM + tid] = v.z;
        P.V_out[(size_t)(row0 + 3) * VDIM + tid] = v.w;
    }
}

// ---------------- batched fnet ----------------
__device__ __forceinline__ void reduce8_256(float4 &a, float4 &b,
                                            float4 *redA, float4 *redB, int tid) {
#pragma unroll
    for (int off = 1; off < 64; off <<= 1) {
        a.x += __shfl_xor(a.x, off, 64); a.y += __shfl_xor(a.y, off, 64);
        a.z += __shfl_xor(a.z, off, 64); a.w += __shfl_xor(a.w, off, 64);
        b.x += __shfl_xor(b.x, off, 64); b.y += __shfl_xor(b.y, off, 64);
        b.z += __shfl_xor(b.z, off, 64); b.w += __shfl_xor(b.w, off, 64);
    }
    int w = tid >> 6;
    if ((tid & 63) == 0) { redA[w] = a; redB[w] = b; }
    __syncthreads();
    int p = w ^ 1;
    a = f4add(redA[w], redA[p]);
    b = f4add(redB[w], redB[p]);
    __syncthreads();
}

template <int K>
__device__ __forceinline__ void flayer(const float *__restrict__ in,
                                       const float *__restrict__ W,
                                       const float *__restrict__ bias,
                                       const float *__restrict__ gam,
                                       const float *__restrict__ bet,
                                       float *__restrict__ out,
                                       float4 *redA, float4 *redB, int tid) {
    const int rh = tid >> 7, cq = tid & 127;
    const float4 *Wv = (const float4 *)W + cq;
    float4 accA[4], accB[4];
#pragma unroll
    for (int j = 0; j < 4; ++j) { accA[j] = f4zero(); accB[j] = f4zero(); }
#pragma unroll 4
    for (int k = 0; k < K; ++k) {
        float4 w = Wv[(size_t)k * (HDIM / 4)];
        const float *ip = in + k * FROWS + 8 * rh;
        float4 aA = *(const float4 *)ip;
        float4 aB = *(const float4 *)(ip + 4);
        accA[0] = f4fma(aA, w.x, accA[0]); accB[0] = f4fma(aB, w.x, accB[0]);
        accA[1] = f4fma(aA, w.y, accA[1]); accB[1] = f4fma(aB, w.y, accB[1]);
        accA[2] = f4fma(aA, w.z, accA[2]); accB[2] = f4fma(aB, w.z, accB[2]);
        accA[3] = f4fma(aA, w.w, accA[3]); accB[3] = f4fma(aB, w.w, accB[3]);
    }
    float4 b4 = ((const float4 *)bias)[cq];
    float bb[4] = {b4.x, b4.y, b4.z, b4.w};
#pragma unroll
    for (int j = 0; j < 4; ++j) {
        accA[j].x += bb[j]; accA[j].y += bb[j]; accA[j].z += bb[j]; accA[j].w += bb[j];
        accB[j].x += bb[j]; accB[j].y += bb[j]; accB[j].z += bb[j]; accB[j].w += bb[j];
    }
    const float inv = 1.f / (float)HDIM;
    float4 sA = f4add(f4add(accA[0], accA[1]), f4add(accA[2], accA[3]));
    float4 sB = f4add(f4add(accB[0], accB[1]), f4add(accB[2], accB[3]));
    reduce8_256(sA, sB, redA, redB, tid);
    float4 mA = f4scale(sA, inv), mB = f4scale(sB, inv);
    float4 dA[4], dB[4];
    float4 qA = f4zero(), qB = f4zero();
#pragma unroll
    for (int j = 0; j < 4; ++j) {
        dA[j] = f4sub(accA[j], mA);
        dB[j] = f4sub(accB[j], mB);
        qA.x += dA[j].x * dA[j].x; qA.y += dA[j].y * dA[j].y;
        qA.z += dA[j].z * dA[j].z; qA.w += dA[j].w * dA[j].w;
        qB.x += dB[j].x * dB[j].x; qB.y += dB[j].y * dB[j].y;
        qB.z += dB[j].z * dB[j].z; qB.w += dB[j].w * dB[j].w;
    }
    reduce8_256(qA, qB, redA, redB, tid);
    float4 rsA, rsB;
    rsA.x = 1.f / sqrtf(qA.x * inv + LN_EPS); rsA.y = 1.f / sqrtf(qA.y * inv + LN_EPS);
    rsA.z = 1.f / sqrtf(qA.z * inv + LN_EPS); rsA.w = 1.f / sqrtf(qA.w * inv + LN_EPS);
    rsB.x = 1.f / sqrtf(qB.x * inv + LN_EPS); rsB.y = 1.f / sqrtf(qB.y * inv + LN_EPS);
    rsB.z = 1.f / sqrtf(qB.z * inv + LN_EPS); rsB.w = 1.f / sqrtf(qB.w * inv + LN_EPS);
    float4 g4 = ((const float4 *)gam)[cq];
    float4 e4 = ((const float4 *)bet)[cq];
    float gg[4] = {g4.x, g4.y, g4.z, g4.w};
    float ee[4] = {e4.x, e4.y, e4.z, e4.w};
#pragma unroll
    for (int j = 0; j < 4; ++j) {
        float4 hA, hB;
        hA.x = fmaxf(fmaf(dA[j].x * rsA.x, gg[j], ee[j]), 0.f);
        hA.y = fmaxf(fmaf(dA[j].y * rsA.y, gg[j], ee[j]), 0.f);
        hA.z = fmaxf(fmaf(dA[j].z * rsA.z, gg[j], ee[j]), 0.f);
        hA.w = fmaxf(fmaf(dA[j].w * rsA.w, gg[j], ee[j]), 0.f);
        hB.x = fmaxf(fmaf(dB[j].x * rsB.x, gg[j], ee[j]), 0.f);
        hB.y = fmaxf(fmaf(dB[j].y * rsB.y, gg[j], ee[j]), 0.f);
        hB.z = fmaxf(fmaf(dB[j].z * rsB.z, gg[j], ee[j]), 0.f);
        hB.w = fmaxf(fmaf(dB[j].w * rsB.w, gg[j], ee[j]), 0.f);
        float *op = out + (4 * cq + j) * FROWS + 8 * rh;
        *(float4 *)op = hA;
        *(float4 *)(op + 4) = hB;
    }
    __syncthreads();
}

__global__ __launch_bounds__(FNT) void gfn_fnet(Params P) {
    __shared__ float Vt[VDIM * FROWS];     // 8KB  [k][16]
    __shared__ float A[HDIM * FROWS];      // 32KB [c][16]
    __shared__ int ord[VDIM];
    __shared__ int invp[VDIM];
    __shared__ float4 redA[4], redB[4];

    const int tid = threadIdx.x;
    const int t = blockIdx.x >> 5;             // step 0..127
    const int r0 = (blockIdx.x & 31) * FROWS;  // row offset

    if (tid < VDIM) ord[tid] = P.top_order[tid];
    __syncthreads();
    if (tid < VDIM) invp[ord[tid]] = tid;
    __syncthreads();
    for (int idx = tid; idx < VDIM * FROWS; idx += FNT) {
        int k = idx >> 4, row = idx & 15;
        int s = invp[k];
        Vt[idx] = (s <= t) ? P.vs[s * BATCH + r0 + row] : 0.f;
    }
    __syncthreads();

    flayer<VDIM>(Vt, P.f_w1, P.f_b1, P.f_g1, P.f_be1, A, redA, redB, tid);
    flayer<HDIM>(A, P.f_w2, P.f_b2, P.f_g2, P.f_be2, A, redA, redB, tid);
    flayer<HDIM>(A, P.f_w3, P.f_b3, P.f_g3, P.f_be3, A, redA, redB, tid);

    const int rh = tid >> 7, cq = tid & 127;
    float4 w4 = ((const float4 *)P.f_w4)[cq];
    float ww[4] = {w4.x, w4.y, w4.z, w4.w};
    float4 sA = f4zero(), sB = f4zero();
#pragma unroll
    for (int j = 0; j < 4; ++j) {
        const float *ap = A + (4 * cq + j) * FROWS + 8 * rh;
        float4 aA = *(const float4 *)ap;
        float4 aB = *(const float4 *)(ap + 4);
        sA = f4fma(aA, ww[j], sA);
        sB = f4fma(aB, ww[j], sB);
    }
    reduce8_256(sA, sB, redA, redB, tid);
    if (cq == 0) {
        float b4v = P.f_b4[0];
        float *dst = P.lf + (size_t)t * BATCH + r0 + 8 * rh;
        dst[0] = sA.x + b4v; dst[1] = sA.y + b4v;
        dst[2] = sA.z + b4v; dst[3] = sA.w + b4v;
        dst[4] = sB.x + b4v; dst[5] = sB.y + b4v;
        dst[6] = sB.z + b4v; dst[7] = sB.w + b4v;
    }
}

// ---------------- loss ----------------
__global__ __launch_bounds__(NT) void gfn_loss(Params P) {
    __shared__ float H1[HDIM], H2[HDIM];
    __shared__ float red1[8];
    const int tid = threadIdx.x;
    const float inv = 1.f / (float)HDIM;

    float z = P.f_b1[tid];
    float m = block_reduce1(z, red1, tid) * inv;
    float d = z - m;
    float var = block_reduce1(d * d, red1, tid) * inv;
    float h = fmaxf(fmaf(d * (1.f / sqrtf(var + LN_EPS)), P.f_g1[tid], P.f_be1[tid]), 0.f);
    H1[tid] = h;
    __syncthreads();

    float acc = 0.f;
    for (int k = 0; k < HDIM; ++k) acc = fmaf(H1[k], P.f_w2[(size_t)k * HDIM + tid], acc);
    z = acc + P.f_b2[tid];
    m = block_reduce1(z, red1, tid) * inv;
    d = z - m;
    var = block_reduce1(d * d, red1, tid) * inv;
    h = fmaxf(fmaf(d * (1.f / sqrtf(var + LN_EPS)), P.f_g2[tid], P.f_be2[tid]), 0.f);
    H2[tid] = h;
    __syncthreads();

    acc = 0.f;
    for (int k = 0; k < HDIM; ++k) acc = fmaf(H2[k], P.f_w3[(size_t)k * HDIM + tid], acc);
    z = acc + P.f_b3[tid];
    m = block_reduce1(z, red1, tid) * inv;
    d = z - m;
    var = block_reduce1(d * d, red1, tid) * inv;
    h = fmaxf(fmaf(d * (1.f / sqrtf(var + LN_EPS)), P.f_g3[tid], P.f_be3[tid]), 0.f);
    float F0 = block_reduce1(h * P.f_w4[tid], red1, tid) + P.f_b4[0];

    const int b = tid;
    float lfp = F0;
    float s = 0.f;
    for (int t = 0; t < VDIM; ++t) {
        float lp = P.lp[t * BATCH + b];
        float lfn = (t == VDIM - 1) ? P.score[b] : P.lf[t * BATCH + b];
        float dd = lfp + lp - lfn;
        s = fmaf(dd, dd, s);
        lfp = lfn;
    }
    s *= (1.f / (float)VDIM);
    float total = block_reduce1(s, red1, tid) * (1.f / (float)BATCH);
    if (tid == 0) P.loss[0] = total;
}

extern "C" void kernel_launch(void *const *d_in, const int *in_sizes, int n_in,
                              void *d_out, int out_size, void *d_ws, size_t ws_size,
                              hipStream_t stream) {
    Params P;
    P.u     = (const float *)d_in[0];
    P.q_w1  = (const float *)d_in[1];
    P.q_b1  = (const float *)d_in[2];
    P.q_g1  = (const float *)d_in[3];
    P.q_be1 = (const float *)d_in[4];
    P.q_w2  = (const float *)d_in[5];
    P.q_b2  = (const float *)d_in[6];
    P.q_g2  = (const float *)d_in[7];
    P.q_be2 = (const float *)d_in[8];
    P.q_w3  = (const float *)d_in[9];
    P.q_b3  = (const float *)d_in[10];
    P.q_g3  = (const float *)d_in[11];
    P.q_be3 = (const float *)d_in[12];
    P.q_W   = (const float *)d_in[13];
    P.q_bias= (const float *)d_in[14];
    P.q_marg= (const float *)d_in[15];
    P.f_w1  = (const float *)d_in[16];
    P.f_b1  = (const float *)d_in[17];
    P.f_g1  = (const float *)d_in[18];
    P.f_be1 = (const float *)d_in[19];
    P.f_w2  = (const float *)d_in[20];
    P.f_b2  = (const float *)d_in[21];
    P.f_g2  = (const float *)d_in[22];
    P.f_be2 = (const float *)d_in[23];
    P.f_w3  = (const float *)d_in[24];
    P.f_b3  = (const float *)d_in[25];
    P.f_g3  = (const float *)d_in[26];
    P.f_be3 = (const float *)d_in[27];
    P.f_w4  = (const float *)d_in[28];
    P.f_b4  = (const float *)d_in[29];
    P.J     = (const float *)d_in[30];
    P.top_order = (const int *)d_in[31];
    P.pa_mask   = (const int *)d_in[32];

    float *ws = (float *)d_ws;
    P.V_out = (float *)d_out;
    P.loss  = (float *)d_out + (size_t)BATCH * VDIM;
    P.lp    = ws;                                       // [128][512]
    P.lf    = ws + (size_t)VDIM * BATCH;                // [128][512]
    P.score = ws + 2 * (size_t)VDIM * BATCH;            // [512]
    P.vs    = ws + 2 * (size_t)VDIM * BATCH + BATCH;    // [128][512]

    gfn_scan<<<dim3(NBLK), dim3(NT), 0, stream>>>(P);
    gfn_fnet<<<dim3(FGRID), dim3(FNT), 0, stream>>>(P);
    gfn_loss<<<dim3(1), dim3(NT), 0, stream>>>(P);
}

// Round 6
// 4344.099 us; speedup vs baseline: 1.0832x; 1.0832x over previous
//
#include <hip/hip_runtime.h>
#include <hip/hip_bf16.h>
#include <math.h>

#define VDIM 128
#define HDIM 512
#define BATCH 512
#define RPB 4                  // batch rows per scan block
#define NBLK (BATCH / RPB)     // 128 scan blocks
#define NWORK 128              // persistent fnet worker blocks
#define NT 512
#define NWAVE 8
#define LN_EPS 1e-5f
#define FROWS 32               // fnet rows per tile
#define NGRP (BATCH / FROWS)   // 16 row groups
#define SBPG (FROWS / RPB)     // 8 scan blocks per row group

// ---------- float4 helpers ----------
__device__ __forceinline__ float4 f4zero() { return make_float4(0.f, 0.f, 0.f, 0.f); }
__device__ __forceinline__ float4 f4add(float4 a, float4 b) {
    return make_float4(a.x + b.x, a.y + b.y, a.z + b.z, a.w + b.w);
}
__device__ __forceinline__ float4 f4fma(float4 a, float s, float4 c) {
    return make_float4(fmaf(a.x, s, c.x), fmaf(a.y, s, c.y),
                       fmaf(a.z, s, c.z), fmaf(a.w, s, c.w));
}
__device__ __forceinline__ float4 f4scale(float4 a, float s) {
    return make_float4(a.x * s, a.y * s, a.z * s, a.w * s);
}
__device__ __forceinline__ float4 f4sub(float4 a, float4 b) {
    return make_float4(a.x - b.x, a.y - b.y, a.z - b.z, a.w - b.w);
}
__device__ __forceinline__ float f4get(float4 v, int r) {
    return r == 0 ? v.x : r == 1 ? v.y : r == 2 ? v.z : v.w;
}

struct Params {
    const float *u;
    const float *q_w1, *q_b1, *q_g1, *q_be1;
    const float *q_w2, *q_b2, *q_g2, *q_be2;
    const float *q_w3, *q_b3, *q_g3, *q_be3;
    const float *q_W, *q_bias, *q_marg;
    const float *f_w1, *f_b1, *f_g1, *f_be1;
    const float *f_w2, *f_b2, *f_g2, *f_be2;
    const float *f_w3, *f_b3, *f_g3, *f_be3;
    const float *f_w4, *f_b4, *J;
    const int *top_order, *pa_mask;
    int *flag;
    float *V_out, *lp, *lf, *score, *vs, *loss;
};

// ---------------- shared-memory roles (union -> 83.2KB -> 1 block/CU) ----
struct ScanS {
    float4 VT[VDIM];           // V^T: [col] -> 4 rows
    float4 VPT[VDIM];          // permuted layer-1 input
    float4 ATa[HDIM];          // permuted activations (index st(c)=(c&3)*128+(c>>2))
    float4 ATb[HDIM];
    float4 part[4][4][128];    // [j][ks][cb]  32KB
    float4 redA[NWAVE], redB[NWAVE];
};
struct WorkS {
    float Vt[VDIM * FROWS];    // 16KB [k][32]
    float A[HDIM * FROWS];     // 64KB [c][32]
    int ord[VDIM], invp[VDIM];
    float4 redA[NWAVE], redB[NWAVE];
};
union SMem { ScanS s; WorkS w; };

// ---- block-wide f4 allreduce, ONE sync (caller rotates redA/redB) ------
__device__ __forceinline__ float4 allreduce4_1s(float4 v, float4 *red, int tid) {
#pragma unroll
    for (int off = 1; off < 64; off <<= 1) {
        v.x += __shfl_xor(v.x, off, 64);
        v.y += __shfl_xor(v.y, off, 64);
        v.z += __shfl_xor(v.z, off, 64);
        v.w += __shfl_xor(v.w, off, 64);
    }
    if ((tid & 63) == 0) red[tid >> 6] = v;
    __syncthreads();
    float4 s = red[0];
#pragma unroll
    for (int w = 1; w < NWAVE; ++w) s = f4add(s, red[w]);
    return s;   // NO trailing sync: next red-write is >=1 sync away by construction
}

__device__ __forceinline__ float block_reduce1(float v, float *red, int tid) {
#pragma unroll
    for (int off = 1; off < 64; off <<= 1) v += __shfl_xor(v, off, 64);
    if ((tid & 63) == 0) red[tid >> 6] = v;
    __syncthreads();
    float s = 0.f;
#pragma unroll
    for (int w = 0; w < NWAVE; ++w) s += red[w];
    __syncthreads();
    return s;
}

// ---- pair-wave reduce for worker (rows grouped 2 waves) ----------------
__device__ __forceinline__ void redpair(float4 &a, float4 &b,
                                        float4 *redA, float4 *redB, int tid) {
#pragma unroll
    for (int off = 1; off < 64; off <<= 1) {
        a.x += __shfl_xor(a.x, off, 64); a.y += __shfl_xor(a.y, off, 64);
        a.z += __shfl_xor(a.z, off, 64); a.w += __shfl_xor(a.w, off, 64);
        b.x += __shfl_xor(b.x, off, 64); b.y += __shfl_xor(b.y, off, 64);
        b.z += __shfl_xor(b.z, off, 64); b.w += __shfl_xor(b.w, off, 64);
    }
    int w = tid >> 6;
    if ((tid & 63) == 0) { redA[w] = a; redB[w] = b; }
    __syncthreads();
    int p = w ^ 1;
    a = f4add(redA[w], redA[p]);
    b = f4add(redB[w], redB[p]);
    __syncthreads();
}

// ---------------- scan GEMV+LN (4-way K-split, permuted activations) ----
// inA: permuted input, segment m holds cols with c&3==m at index m*(K/4)+(c>>2).
// Wave-pair ks=tid>>7 owns K-chunk; cq=tid&127 owns col f4-block.
// Combine/LN: thread tid owns column myc = 4*(tid&127)+(tid>>7); h stored
// at outA[tid] which IS st(myc) -> next layer's permuted read is consistent.
template <int K>
__device__ __forceinline__ void gemv_ln_scan(const float4 *__restrict__ inA,
                                             const float *__restrict__ W,
                                             const float *__restrict__ bias,
                                             const float *__restrict__ gam,
                                             const float *__restrict__ bet,
                                             float4 *__restrict__ outA,
                                             ScanS &S, int tid, int ks, int cq,
                                             int myc) {
    constexpr int kc = K / 4;      // rows per ks-chunk
    constexpr int q4 = kc / 4;
    constexpr int seg = K / 4;     // permuted segment stride
    const float4 *Wp = (const float4 *)W + (size_t)(ks * kc) * (HDIM / 4) + cq;
    const float4 *ap = inA + ks * q4;
    float4 acc0 = f4zero(), acc1 = f4zero(), acc2 = f4zero(), acc3 = f4zero();
#pragma unroll 2
    for (int q = 0; q < q4; ++q) {
        float4 a0 = ap[q];                 // LDS b128 broadcast (k = ks*kc+4q+0)
        float4 a1 = ap[q + seg];           // k = ..+1
        float4 a2 = ap[q + 2 * seg];       // k = ..+2
        float4 a3 = ap[q + 3 * seg];       // k = ..+3
        float4 w0 = Wp[(size_t)(4 * q + 0) * (HDIM / 4)];   // 1KB/wave coalesced
        float4 w1 = Wp[(size_t)(4 * q + 1) * (HDIM / 4)];
        float4 w2 = Wp[(size_t)(4 * q + 2) * (HDIM / 4)];
        float4 w3 = Wp[(size_t)(4 * q + 3) * (HDIM / 4)];
        acc0 = f4fma(a0, w0.x, acc0); acc1 = f4fma(a0, w0.y, acc1);
        acc2 = f4fma(a0, w0.z, acc2); acc3 = f4fma(a0, w0.w, acc3);
        acc0 = f4fma(a1, w1.x, acc0); acc1 = f4fma(a1, w1.y, acc1);
        acc2 = f4fma(a1, w1.z, acc2); acc3 = f4fma(a1, w1.w, acc3);
        acc0 = f4fma(a2, w2.x, acc0); acc1 = f4fma(a2, w2.y, acc1);
        acc2 = f4fma(a2, w2.z, acc2); acc3 = f4fma(a2, w2.w, acc3);
        acc0 = f4fma(a3, w3.x, acc0); acc1 = f4fma(a3, w3.y, acc1);
        acc2 = f4fma(a3, w3.z, acc2); acc3 = f4fma(a3, w3.w, acc3);
    }
    // conflict-free partial writes (lane stride 16B per j)
    S.part[0][ks][cq] = acc0;
    S.part[1][ks][cq] = acc1;
    S.part[2][ks][cq] = acc2;
    S.part[3][ks][cq] = acc3;
    __syncthreads();
    // combine (conflict-free reads: per 2-wave group j fixed, cb contiguous)
    const int j = ks, cb = cq;     // same decomposition of tid
    float4 acc = f4add(f4add(S.part[j][0][cb], S.part[j][1][cb]),
                       f4add(S.part[j][2][cb], S.part[j][3][cb]));
    float bc = bias[myc];
    acc.x += bc; acc.y += bc; acc.z += bc; acc.w += bc;
    // two-pass LN over 512 columns
    const float inv = 1.f / (float)HDIM;
    float4 m4 = f4scale(allreduce4_1s(acc, S.redA, tid), inv);
    float4 d = f4sub(acc, m4);
    float4 sq = make_float4(d.x * d.x, d.y * d.y, d.z * d.z, d.w * d.w);
    float4 var = f4scale(allreduce4_1s(sq, S.redB, tid), inv);
    float4 rs;
    rs.x = 1.f / sqrtf(var.x + LN_EPS);
    rs.y = 1.f / sqrtf(var.y + LN_EPS);
    rs.z = 1.f / sqrtf(var.z + LN_EPS);
    rs.w = 1.f / sqrtf(var.w + LN_EPS);
    float gc = gam[myc], ec = bet[myc];
    float4 h;
    h.x = fmaxf(fmaf(d.x * rs.x, gc, ec), 0.f);
    h.y = fmaxf(fmaf(d.y * rs.y, gc, ec), 0.f);
    h.z = fmaxf(fmaf(d.z * rs.z, gc, ec), 0.f);
    h.w = fmaxf(fmaf(d.w * rs.w, gc, ec), 0.f);
    outA[tid] = h;                 // contiguous write = st(myc)
    __syncthreads();
}

// ---------------- scan role: qtrunk + sampling, publishes vs + flags ----
__device__ void scan_role(const Params &P, int bid, ScanS &S) {
    const int tid = threadIdx.x;
    const int ks = tid >> 7;
    const int cq = tid & 127;
    const int myc = 4 * cq + ks;
    const int row0 = bid * RPB;

    if (tid < VDIM) S.VT[tid] = f4zero();
    __syncthreads();

    for (int i = 0; i < VDIM; ++i) {
        const int node = P.top_order[i];

        float4 apv = f4zero();
        if (tid < VDIM) {
            float mk = (float)P.pa_mask[node * VDIM + tid];
            float4 vp = f4scale(S.VT[tid], mk);
            S.VPT[(tid & 3) * 32 + (tid >> 2)] = vp;   // permuted store
            apv = make_float4(fabsf(vp.x), fabsf(vp.y), fabsf(vp.z), fabsf(vp.w));
        }
        float4 asum = allreduce4_1s(apv, S.redB, tid);  // sync publishes VPT

        gemv_ln_scan<VDIM>(S.VPT, P.q_w1, P.q_b1, P.q_g1, P.q_be1, S.ATa, S, tid, ks, cq, myc);
        gemv_ln_scan<HDIM>(S.ATa, P.q_w2, P.q_b2, P.q_g2, P.q_be2, S.ATb, S, tid, ks, cq, myc);
        gemv_ln_scan<HDIM>(S.ATb, P.q_w3, P.q_b3, P.q_g3, P.q_be3, S.ATa, S, tid, ks, cq, myc);

        // head: x[r] = sum_c h3[r][c] * q_W[node][c]
        float wq = P.q_W[(size_t)node * HDIM + myc];
        float4 x4 = allreduce4_1s(f4scale(S.ATa[tid], wq), S.redA, tid);

        if (tid < RPB) {
            const int r = tid;
            float asr = f4get(asum, r);
            float xr = f4get(x4, r) + P.q_bias[node];
            float arg = (asr == 0.f) ? P.q_marg[node] : xr;
            float p = 1.f / (1.f + expf(-arg));
            float uv = P.u[i * BATCH + row0 + r];
            bool samp = uv < p;
            float v = samp ? 1.f : -1.f;
            ((float *)&S.VT[node])[r] = v;
            P.vs[(size_t)i * BATCH + row0 + r] = v;
            P.lp[(size_t)i * BATCH + row0 + r] = samp ? logf(p) : log1pf(-p);
            __threadfence();     // release: vs visible device-wide before flag
        }
        __syncthreads();
        if (tid == 0) atomicExch(P.flag + bid, i + 1);
    }

    // terminal score: V . J . V per row
    float4 inner = f4zero();
    if (tid < VDIM) {
#pragma unroll 4
        for (int ii = 0; ii < VDIM; ++ii)
            inner = f4fma(S.VT[ii], P.J[(size_t)ii * VDIM + tid], inner);
        float4 vc = S.VT[tid];
        inner = make_float4(inner.x * vc.x, inner.y * vc.y, inner.z * vc.z, inner.w * vc.w);
    }
    float4 sc4 = allreduce4_1s(inner, S.redA, tid);
    if (tid < RPB) P.score[row0 + tid] = f4get(sc4, tid);
    if (tid < VDIM) {
        float4 v = S.VT[tid];
        P.V_out[(size_t)(row0 + 0) * VDIM + tid] = v.x;
        P.V_out[(size_t)(row0 + 1) * VDIM + tid] = v.y;
        P.V_out[(size_t)(row0 + 2) * VDIM + tid] = v.z;
        P.V_out[(size_t)(row0 + 3) * VDIM + tid] = v.w;
    }
}

// ---------------- fnet layer, 512 threads, 32-row tile ------------------
template <int K>
__device__ __forceinline__ void flayer512(const float *__restrict__ in,
                                          const float *__restrict__ W,
                                          const float *__restrict__ bias,
                                          const float *__restrict__ gam,
                                          const float *__restrict__ bet,
                                          float *__restrict__ out,
                                          float4 *redA, float4 *redB, int tid) {
    const int rh = tid >> 7;       // row octet: rows 8rh..8rh+7
    const int cq = tid & 127;      // col f4 block
    const float4 *Wv = (const float4 *)W + cq;
    float4 accA[4], accB[4];
#pragma unroll
    for (int j = 0; j < 4; ++j) { accA[j] = f4zero(); accB[j] = f4zero(); }
#pragma unroll 4
    for (int k = 0; k < K; ++k) {
        float4 w = Wv[(size_t)k * (HDIM / 4)];
        const float *ip = in + k * FROWS + 8 * rh;
        float4 vA = *(const float4 *)ip;
        float4 vB = *(const float4 *)(ip + 4);
        accA[0] = f4fma(vA, w.x, accA[0]); accB[0] = f4fma(vB, w.x, accB[0]);
        accA[1] = f4fma(vA, w.y, accA[1]); accB[1] = f4fma(vB, w.y, accB[1]);
        accA[2] = f4fma(vA, w.z, accA[2]); accB[2] = f4fma(vB, w.z, accB[2]);
        accA[3] = f4fma(vA, w.w, accA[3]); accB[3] = f4fma(vB, w.w, accB[3]);
    }
    float4 b4 = ((const float4 *)bias)[cq];
    float bb[4] = {b4.x, b4.y, b4.z, b4.w};
#pragma unroll
    for (int j = 0; j < 4; ++j) {
        accA[j].x += bb[j]; accA[j].y += bb[j]; accA[j].z += bb[j]; accA[j].w += bb[j];
        accB[j].x += bb[j]; accB[j].y += bb[j]; accB[j].z += bb[j]; accB[j].w += bb[j];
    }
    const float inv = 1.f / (float)HDIM;
    float4 sA = f4add(f4add(accA[0], accA[1]), f4add(accA[2], accA[3]));
    float4 sB = f4add(f4add(accB[0], accB[1]), f4add(accB[2], accB[3]));
    redpair(sA, sB, redA, redB, tid);
    float4 mA = f4scale(sA, inv), mB = f4scale(sB, inv);
    float4 dA[4], dB[4];
    float4 qA = f4zero(), qB = f4zero();
#pragma unroll
    for (int j = 0; j < 4; ++j) {
        dA[j] = f4sub(accA[j], mA);
        dB[j] = f4sub(accB[j], mB);
        qA.x += dA[j].x * dA[j].x; qA.y += dA[j].y * dA[j].y;
        qA.z += dA[j].z * dA[j].z; qA.w += dA[j].w * dA[j].w;
        qB.x += dB[j].x * dB[j].x; qB.y += dB[j].y * dB[j].y;
        qB.z += dB[j].z * dB[j].z; qB.w += dB[j].w * dB[j].w;
    }
    redpair(qA, qB, redA, redB, tid);
    float4 rsA, rsB;
    rsA.x = 1.f / sqrtf(qA.x * inv + LN_EPS); rsA.y = 1.f / sqrtf(qA.y * inv + LN_EPS);
    rsA.z = 1.f / sqrtf(qA.z * inv + LN_EPS); rsA.w = 1.f / sqrtf(qA.w * inv + LN_EPS);
    rsB.x = 1.f / sqrtf(qB.x * inv + LN_EPS); rsB.y = 1.f / sqrtf(qB.y * inv + LN_EPS);
    rsB.z = 1.f / sqrtf(qB.z * inv + LN_EPS); rsB.w = 1.f / sqrtf(qB.w * inv + LN_EPS);
    float4 g4 = ((const float4 *)gam)[cq];
    float4 e4 = ((const float4 *)bet)[cq];
    float gg[4] = {g4.x, g4.y, g4.z, g4.w};
    float ee[4] = {e4.x, e4.y, e4.z, e4.w};
#pragma unroll
    for (int j = 0; j < 4; ++j) {
        float4 hA, hB;
        hA.x = fmaxf(fmaf(dA[j].x * rsA.x, gg[j], ee[j]), 0.f);
        hA.y = fmaxf(fmaf(dA[j].y * rsA.y, gg[j], ee[j]), 0.f);
        hA.z = fmaxf(fmaf(dA[j].z * rsA.z, gg[j], ee[j]), 0.f);
        hA.w = fmaxf(fmaf(dA[j].w * rsA.w, gg[j], ee[j]), 0.f);
        hB.x = fmaxf(fmaf(dB[j].x * rsB.x, gg[j], ee[j]), 0.f);
        hB.y = fmaxf(fmaf(dB[j].y * rsB.y, gg[j], ee[j]), 0.f);
        hB.z = fmaxf(fmaf(dB[j].z * rsB.z, gg[j], ee[j]), 0.f);
        hB.w = fmaxf(fmaf(dB[j].w * rsB.w, gg[j], ee[j]), 0.f);
        float *op = out + (4 * cq + j) * FROWS + 8 * rh;
        *(float4 *)op = hA;
        *(float4 *)(op + 4) = hB;
    }
    __syncthreads();
}

// ---------------- worker role: polls scan progress, evaluates fnet ------
__device__ void worker_role(const Params &P, int wid, WorkS &S) {
    const int tid = threadIdx.x;
    if (tid < VDIM) S.ord[tid] = P.top_order[tid];
    __syncthreads();
    if (tid < VDIM) S.invp[S.ord[tid]] = tid;
    __syncthreads();
    const int g = wid & (NGRP - 1);        // fixed row group
    const int r0 = g * FROWS;

    for (int tile = wid; tile < VDIM * NGRP; tile += NWORK) {
        const int t = tile >> 4;           // step
        if (t == VDIM - 1) continue;       // lf[127] replaced by score in loss
        if (tid == 0) {
            const int need = t + 1;
            for (int b = 0; b < SBPG; ++b) {
                while (atomicAdd(P.flag + (SBPG * g + b), 0) < need)
                    __builtin_amdgcn_s_sleep(8);
            }
            __threadfence();               // acquire
        }
        __syncthreads();
        for (int idx = tid; idx < VDIM * FROWS; idx += NT) {
            int k = idx >> 5, rr = idx & (FROWS - 1);
            int s = S.invp[k];
            S.Vt[idx] = (s <= t) ? P.vs[(size_t)s * BATCH + r0 + rr] : 0.f;
        }
        __syncthreads();

        flayer512<VDIM>(S.Vt, P.f_w1, P.f_b1, P.f_g1, P.f_be1, S.A, S.redA, S.redB, tid);
        flayer512<HDIM>(S.A, P.f_w2, P.f_b2, P.f_g2, P.f_be2, S.A, S.redA, S.redB, tid);
        flayer512<HDIM>(S.A, P.f_w3, P.f_b3, P.f_g3, P.f_be3, S.A, S.redA, S.redB, tid);

        const int rh = tid >> 7, cq = tid & 127;
        float4 w4 = ((const float4 *)P.f_w4)[cq];
        float ww[4] = {w4.x, w4.y, w4.z, w4.w};
        float4 sA = f4zero(), sB = f4zero();
#pragma unroll
        for (int j = 0; j < 4; ++j) {
            const float *ap2 = S.A + (4 * cq + j) * FROWS + 8 * rh;
            float4 vA = *(const float4 *)ap2;
            float4 vB = *(const float4 *)(ap2 + 4);
            sA = f4fma(vA, ww[j], sA);
            sB = f4fma(vB, ww[j], sB);
        }
        redpair(sA, sB, S.redA, S.redB, tid);
        if (cq == 0) {
            float b4v = P.f_b4[0];
            float *dst = P.lf + (size_t)t * BATCH + r0 + 8 * rh;
            dst[0] = sA.x + b4v; dst[1] = sA.y + b4v;
            dst[2] = sA.z + b4v; dst[3] = sA.w + b4v;
            dst[4] = sB.x + b4v; dst[5] = sB.y + b4v;
            dst[6] = sB.z + b4v; dst[7] = sB.w + b4v;
        }
        __syncthreads();
    }
}

__global__ __launch_bounds__(NT) void gfn_main(Params P) {
    __shared__ SMem sm;
    if (blockIdx.x < NBLK) scan_role(P, blockIdx.x, sm.s);
    else                   worker_role(P, blockIdx.x - NBLK, sm.w);
}

// ---------------- loss ----------------
__global__ __launch_bounds__(NT) void gfn_loss(Params P) {
    __shared__ float H1[HDIM], H2[HDIM];
    __shared__ float red1[NWAVE];
    const int tid = threadIdx.x;
    const float inv = 1.f / (float)HDIM;

    float z = P.f_b1[tid];
    float m = block_reduce1(z, red1, tid) * inv;
    float d = z - m;
    float var = block_reduce1(d * d, red1, tid) * inv;
    float h = fmaxf(fmaf(d * (1.f / sqrtf(var + LN_EPS)), P.f_g1[tid], P.f_be1[tid]), 0.f);
    H1[tid] = h;
    __syncthreads();

    float acc = 0.f;
    for (int k = 0; k < HDIM; ++k) acc = fmaf(H1[k], P.f_w2[(size_t)k * HDIM + tid], acc);
    z = acc + P.f_b2[tid];
    m = block_reduce1(z, red1, tid) * inv;
    d = z - m;
    var = block_reduce1(d * d, red1, tid) * inv;
    h = fmaxf(fmaf(d * (1.f / sqrtf(var + LN_EPS)), P.f_g2[tid], P.f_be2[tid]), 0.f);
    H2[tid] = h;
    __syncthreads();

    acc = 0.f;
    for (int k = 0; k < HDIM; ++k) acc = fmaf(H2[k], P.f_w3[(size_t)k * HDIM + tid], acc);
    z = acc + P.f_b3[tid];
    m = block_reduce1(z, red1, tid) * inv;
    d = z - m;
    var = block_reduce1(d * d, red1, tid) * inv;
    h = fmaxf(fmaf(d * (1.f / sqrtf(var + LN_EPS)), P.f_g3[tid], P.f_be3[tid]), 0.f);
    float F0 = block_reduce1(h * P.f_w4[tid], red1, tid) + P.f_b4[0];

    const int b = tid;
    float lfp = F0;
    float s = 0.f;
    for (int t = 0; t < VDIM; ++t) {
        float lp = P.lp[(size_t)t * BATCH + b];
        float lfn = (t == VDIM - 1) ? P.score[b] : P.lf[(size_t)t * BATCH + b];
        float dd = lfp + lp - lfn;
        s = fmaf(dd, dd, s);
        lfp = lfn;
    }
    s *= (1.f / (float)VDIM);
    float total = block_reduce1(s, red1, tid) * (1.f / (float)BATCH);
    if (tid == 0) P.loss[0] = total;
}

extern "C" void kernel_launch(void *const *d_in, const int *in_sizes, int n_in,
                              void *d_out, int out_size, void *d_ws, size_t ws_size,
                              hipStream_t stream) {
    Params P;
    P.u     = (const float *)d_in[0];
    P.q_w1  = (const float *)d_in[1];
    P.q_b1  = (const float *)d_in[2];
    P.q_g1  = (const float *)d_in[3];
    P.q_be1 = (const float *)d_in[4];
    P.q_w2  = (const float *)d_in[5];
    P.q_b2  = (const float *)d_in[6];
    P.q_g2  = (const float *)d_in[7];
    P.q_be2 = (const float *)d_in[8];
    P.q_w3  = (const float *)d_in[9];
    P.q_b3  = (const float *)d_in[10];
    P.q_g3  = (const float *)d_in[11];
    P.q_be3 = (const float *)d_in[12];
    P.q_W   = (const float *)d_in[13];
    P.q_bias= (const float *)d_in[14];
    P.q_marg= (const float *)d_in[15];
    P.f_w1  = (const float *)d_in[16];
    P.f_b1  = (const float *)d_in[17];
    P.f_g1  = (const float *)d_in[18];
    P.f_be1 = (const float *)d_in[19];
    P.f_w2  = (const float *)d_in[20];
    P.f_b2  = (const float *)d_in[21];
    P.f_g2  = (const float *)d_in[22];
    P.f_be2 = (const float *)d_in[23];
    P.f_w3  = (const float *)d_in[24];
    P.f_b3  = (const float *)d_in[25];
    P.f_g3  = (const float *)d_in[26];
    P.f_be3 = (const float *)d_in[27];
    P.f_w4  = (const float *)d_in[28];
    P.f_b4  = (const float *)d_in[29];
    P.J     = (const float *)d_in[30];
    P.top_order = (const int *)d_in[31];
    P.pa_mask   = (const int *)d_in[32];

    float *ws = (float *)d_ws;
    P.V_out = (float *)d_out;
    P.loss  = (float *)d_out + (size_t)BATCH * VDIM;
    P.lp    = ws;                                       // [128][512]
    P.lf    = ws + (size_t)VDIM * BATCH;                // [128][512]
    P.score = ws + 2 * (size_t)VDIM * BATCH;            // [512]
    P.vs    = ws + 2 * (size_t)VDIM * BATCH + BATCH;    // [128][512]
    P.flag  = (int *)(ws + 3 * (size_t)VDIM * BATCH + BATCH);  // [128]

    hipMemsetAsync(P.flag, 0, NBLK * sizeof(int), stream);
    gfn_main<<<dim3(NBLK + NWORK), dim3(NT), 0, stream>>>(P);
    gfn_loss<<<dim3(1), dim3(NT), 0, stream>>>(P);
}

// Round 7
// 4173.946 us; speedup vs baseline: 1.1273x; 1.0408x over previous
//
#include <hip/hip_runtime.h>
#include <hip/hip_bf16.h>
#include <math.h>

#define VDIM 128
#define HDIM 512
#define BATCH 512
#define RPB 4                  // batch rows per scan block
#define NBLK (BATCH / RPB)     // 128 scan blocks
#define NWORK 128              // persistent fnet worker blocks
#define NT 512
#define NWAVE 8
#define LN_EPS 1e-5f
#define FROWS 32               // fnet rows per tile
#define NGRP (BATCH / FROWS)   // 16 row groups
#define SBPG (FROWS / RPB)     // 8 scan blocks per row group

// ---------- float4 helpers ----------
__device__ __forceinline__ float4 f4zero() { return make_float4(0.f, 0.f, 0.f, 0.f); }
__device__ __forceinline__ float4 f4add(float4 a, float4 b) {
    return make_float4(a.x + b.x, a.y + b.y, a.z + b.z, a.w + b.w);
}
__device__ __forceinline__ float4 f4fma(float4 a, float s, float4 c) {
    return make_float4(fmaf(a.x, s, c.x), fmaf(a.y, s, c.y),
                       fmaf(a.z, s, c.z), fmaf(a.w, s, c.w));
}
__device__ __forceinline__ float4 f4scale(float4 a, float s) {
    return make_float4(a.x * s, a.y * s, a.z * s, a.w * s);
}
__device__ __forceinline__ float4 f4sub(float4 a, float4 b) {
    return make_float4(a.x - b.x, a.y - b.y, a.z - b.z, a.w - b.w);
}
__device__ __forceinline__ float f4get(float4 v, int r) {
    return r == 0 ? v.x : r == 1 ? v.y : r == 2 ? v.z : v.w;
}

struct Params {
    const float *u;
    const float *q_w1, *q_b1, *q_g1, *q_be1;
    const float *q_w2, *q_b2, *q_g2, *q_be2;
    const float *q_w3, *q_b3, *q_g3, *q_be3;
    const float *q_W, *q_bias, *q_marg;
    const float *f_w1, *f_b1, *f_g1, *f_be1;
    const float *f_w2, *f_b2, *f_g2, *f_be2;
    const float *f_w3, *f_b3, *f_g3, *f_be3;
    const float *f_w4, *f_b4, *J;
    const int *top_order, *pa_mask;
    int *flag;
    float *V_out, *lp, *lf, *score, *vs, *loss;
};

// ---------------- shared-memory roles (union -> 83.2KB -> 1 block/CU) ----
struct ScanS {
    float4 VT[VDIM];           // V^T: [col] -> 4 rows
    float4 VPT[VDIM];          // permuted layer-1 input
    float4 ATa[HDIM];          // permuted activations (index st(c)=(c&3)*128+(c>>2))
    float4 ATb[HDIM];
    float4 part[4][4][128];    // [j][ks][cb]  32KB
    float4 redA[NWAVE], redB[NWAVE];
};
struct WorkS {
    float Vt[VDIM * FROWS];    // 16KB [k][32]
    float A[HDIM * FROWS];     // 64KB [c][32]
    int ord[VDIM], invp[VDIM];
    float4 redA[NWAVE], redB[NWAVE];
};
union SMem { ScanS s; WorkS w; };

// ---- block-wide f4 allreduce, ONE sync (caller rotates redA/redB) ------
__device__ __forceinline__ float4 allreduce4_1s(float4 v, float4 *red, int tid) {
#pragma unroll
    for (int off = 1; off < 64; off <<= 1) {
        v.x += __shfl_xor(v.x, off, 64);
        v.y += __shfl_xor(v.y, off, 64);
        v.z += __shfl_xor(v.z, off, 64);
        v.w += __shfl_xor(v.w, off, 64);
    }
    if ((tid & 63) == 0) red[tid >> 6] = v;
    __syncthreads();
    float4 s = red[0];
#pragma unroll
    for (int w = 1; w < NWAVE; ++w) s = f4add(s, red[w]);
    return s;   // NO trailing sync: next red-write is >=1 sync away by construction
}

__device__ __forceinline__ float block_reduce1(float v, float *red, int tid) {
#pragma unroll
    for (int off = 1; off < 64; off <<= 1) v += __shfl_xor(v, off, 64);
    if ((tid & 63) == 0) red[tid >> 6] = v;
    __syncthreads();
    float s = 0.f;
#pragma unroll
    for (int w = 0; w < NWAVE; ++w) s += red[w];
    __syncthreads();
    return s;
}

// ---- pair-wave reduce for worker (rows grouped 2 waves) ----------------
__device__ __forceinline__ void redpair(float4 &a, float4 &b,
                                        float4 *redA, float4 *redB, int tid) {
#pragma unroll
    for (int off = 1; off < 64; off <<= 1) {
        a.x += __shfl_xor(a.x, off, 64); a.y += __shfl_xor(a.y, off, 64);
        a.z += __shfl_xor(a.z, off, 64); a.w += __shfl_xor(a.w, off, 64);
        b.x += __shfl_xor(b.x, off, 64); b.y += __shfl_xor(b.y, off, 64);
        b.z += __shfl_xor(b.z, off, 64); b.w += __shfl_xor(b.w, off, 64);
    }
    int w = tid >> 6;
    if ((tid & 63) == 0) { redA[w] = a; redB[w] = b; }
    __syncthreads();
    int p = w ^ 1;
    a = f4add(redA[w], redA[p]);
    b = f4add(redB[w], redB[p]);
    __syncthreads();
}

// ---------------- scan GEMV+LN (4-way K-split, permuted activations) ----
template <int K>
__device__ __forceinline__ void gemv_ln_scan(const float4 *__restrict__ inA,
                                             const float *__restrict__ W,
                                             const float *__restrict__ bias,
                                             const float *__restrict__ gam,
                                             const float *__restrict__ bet,
                                             float4 *__restrict__ outA,
                                             ScanS &S, int tid, int ks, int cq,
                                             int myc) {
    constexpr int kc = K / 4;      // rows per ks-chunk
    constexpr int q4 = kc / 4;
    constexpr int seg = K / 4;     // permuted segment stride
    const float4 *Wp = (const float4 *)W + (size_t)(ks * kc) * (HDIM / 4) + cq;
    const float4 *ap = inA + ks * q4;
    float4 acc0 = f4zero(), acc1 = f4zero(), acc2 = f4zero(), acc3 = f4zero();
#pragma unroll 4
    for (int q = 0; q < q4; ++q) {
        float4 a0 = ap[q];                 // LDS b128 broadcast (k = ks*kc+4q+0)
        float4 a1 = ap[q + seg];           // k = ..+1
        float4 a2 = ap[q + 2 * seg];       // k = ..+2
        float4 a3 = ap[q + 3 * seg];       // k = ..+3
        float4 w0 = Wp[(size_t)(4 * q + 0) * (HDIM / 4)];   // 1KB/wave coalesced
        float4 w1 = Wp[(size_t)(4 * q + 1) * (HDIM / 4)];
        float4 w2 = Wp[(size_t)(4 * q + 2) * (HDIM / 4)];
        float4 w3 = Wp[(size_t)(4 * q + 3) * (HDIM / 4)];
        acc0 = f4fma(a0, w0.x, acc0); acc1 = f4fma(a0, w0.y, acc1);
        acc2 = f4fma(a0, w0.z, acc2); acc3 = f4fma(a0, w0.w, acc3);
        acc0 = f4fma(a1, w1.x, acc0); acc1 = f4fma(a1, w1.y, acc1);
        acc2 = f4fma(a1, w1.z, acc2); acc3 = f4fma(a1, w1.w, acc3);
        acc0 = f4fma(a2, w2.x, acc0); acc1 = f4fma(a2, w2.y, acc1);
        acc2 = f4fma(a2, w2.z, acc2); acc3 = f4fma(a2, w2.w, acc3);
        acc0 = f4fma(a3, w3.x, acc0); acc1 = f4fma(a3, w3.y, acc1);
        acc2 = f4fma(a3, w3.z, acc2); acc3 = f4fma(a3, w3.w, acc3);
    }
    // conflict-free partial writes (lane stride 16B per j)
    S.part[0][ks][cq] = acc0;
    S.part[1][ks][cq] = acc1;
    S.part[2][ks][cq] = acc2;
    S.part[3][ks][cq] = acc3;
    __syncthreads();
    // combine (conflict-free reads: per 2-wave group j fixed, cb contiguous)
    const int j = ks, cb = cq;     // same decomposition of tid
    float4 acc = f4add(f4add(S.part[j][0][cb], S.part[j][1][cb]),
                       f4add(S.part[j][2][cb], S.part[j][3][cb]));
    float bc = bias[myc];
    acc.x += bc; acc.y += bc; acc.z += bc; acc.w += bc;
    // two-pass LN over 512 columns
    const float inv = 1.f / (float)HDIM;
    float4 m4 = f4scale(allreduce4_1s(acc, S.redA, tid), inv);
    float4 d = f4sub(acc, m4);
    float4 sq = make_float4(d.x * d.x, d.y * d.y, d.z * d.z, d.w * d.w);
    float4 var = f4scale(allreduce4_1s(sq, S.redB, tid), inv);
    float4 rs;
    rs.x = 1.f / sqrtf(var.x + LN_EPS);
    rs.y = 1.f / sqrtf(var.y + LN_EPS);
    rs.z = 1.f / sqrtf(var.z + LN_EPS);
    rs.w = 1.f / sqrtf(var.w + LN_EPS);
    float gc = gam[myc], ec = bet[myc];
    float4 h;
    h.x = fmaxf(fmaf(d.x * rs.x, gc, ec), 0.f);
    h.y = fmaxf(fmaf(d.y * rs.y, gc, ec), 0.f);
    h.z = fmaxf(fmaf(d.z * rs.z, gc, ec), 0.f);
    h.w = fmaxf(fmaf(d.w * rs.w, gc, ec), 0.f);
    outA[tid] = h;                 // contiguous write = st(myc)
    __syncthreads();
}

// ---------------- scan role: qtrunk + sampling, publishes vs + flags ----
__device__ void scan_role(const Params &P, int bid, ScanS &S) {
    const int tid = threadIdx.x;
    const int ks = tid >> 7;
    const int cq = tid & 127;
    const int myc = 4 * cq + ks;
    const int row0 = bid * RPB;

    if (tid < VDIM) S.VT[tid] = f4zero();
    __syncthreads();

    for (int i = 0; i < VDIM; ++i) {
        const int node = P.top_order[i];

        float4 apv = f4zero();
        if (tid < VDIM) {
            float mk = (float)P.pa_mask[node * VDIM + tid];
            float4 vp = f4scale(S.VT[tid], mk);
            S.VPT[(tid & 3) * 32 + (tid >> 2)] = vp;   // permuted store
            apv = make_float4(fabsf(vp.x), fabsf(vp.y), fabsf(vp.z), fabsf(vp.w));
        }
        float4 asum = allreduce4_1s(apv, S.redB, tid);  // sync publishes VPT

        gemv_ln_scan<VDIM>(S.VPT, P.q_w1, P.q_b1, P.q_g1, P.q_be1, S.ATa, S, tid, ks, cq, myc);
        gemv_ln_scan<HDIM>(S.ATa, P.q_w2, P.q_b2, P.q_g2, P.q_be2, S.ATb, S, tid, ks, cq, myc);
        gemv_ln_scan<HDIM>(S.ATb, P.q_w3, P.q_b3, P.q_g3, P.q_be3, S.ATa, S, tid, ks, cq, myc);

        // head: x[r] = sum_c h3[r][c] * q_W[node][c]
        float wq = P.q_W[(size_t)node * HDIM + myc];
        float4 x4 = allreduce4_1s(f4scale(S.ATa[tid], wq), S.redA, tid);

        if (tid < RPB) {
            const int r = tid;
            float asr = f4get(asum, r);
            float xr = f4get(x4, r) + P.q_bias[node];
            float arg = (asr == 0.f) ? P.q_marg[node] : xr;
            float p = 1.f / (1.f + expf(-arg));
            float uv = P.u[i * BATCH + row0 + r];
            bool samp = uv < p;
            float v = samp ? 1.f : -1.f;
            ((float *)&S.VT[node])[r] = v;
            // publish at agent coherence point (no L2 dirty line, no inv needed)
            __hip_atomic_store(&P.vs[(size_t)i * BATCH + row0 + r], v,
                               __ATOMIC_RELAXED, __HIP_MEMORY_SCOPE_AGENT);
            P.lp[(size_t)i * BATCH + row0 + r] = samp ? logf(p) : log1pf(-p);
        }
        __syncthreads();
        if (tid == 0) {
            // release: waitcnt + wbl2 (dirty-line writeback only; clean weight
            // lines in L2 stay resident -- NO buffer_inv on this path)
            __hip_atomic_store(P.flag + bid, i + 1,
                               __ATOMIC_RELEASE, __HIP_MEMORY_SCOPE_AGENT);
        }
    }

    // terminal score: V . J . V per row
    float4 inner = f4zero();
    if (tid < VDIM) {
#pragma unroll 4
        for (int ii = 0; ii < VDIM; ++ii)
            inner = f4fma(S.VT[ii], P.J[(size_t)ii * VDIM + tid], inner);
        float4 vc = S.VT[tid];
        inner = make_float4(inner.x * vc.x, inner.y * vc.y, inner.z * vc.z, inner.w * vc.w);
    }
    float4 sc4 = allreduce4_1s(inner, S.redA, tid);
    if (tid < RPB) P.score[row0 + tid] = f4get(sc4, tid);
    if (tid < VDIM) {
        float4 v = S.VT[tid];
        P.V_out[(size_t)(row0 + 0) * VDIM + tid] = v.x;
        P.V_out[(size_t)(row0 + 1) * VDIM + tid] = v.y;
        P.V_out[(size_t)(row0 + 2) * VDIM + tid] = v.z;
        P.V_out[(size_t)(row0 + 3) * VDIM + tid] = v.w;
    }
}

// ---------------- fnet layer, 512 threads, 32-row tile ------------------
template <int K>
__device__ __forceinline__ void flayer512(const float *__restrict__ in,
                                          const float *__restrict__ W,
                                          const float *__restrict__ bias,
                                          const float *__restrict__ gam,
                                          const float *__restrict__ bet,
                                          float *__restrict__ out,
                                          float4 *redA, float4 *redB, int tid) {
    const int rh = tid >> 7;       // row octet: rows 8rh..8rh+7
    const int cq = tid & 127;      // col f4 block
    const float4 *Wv = (const float4 *)W + cq;
    float4 accA[4], accB[4];
#pragma unroll
    for (int j = 0; j < 4; ++j) { accA[j] = f4zero(); accB[j] = f4zero(); }
#pragma unroll 4
    for (int k = 0; k < K; ++k) {
        float4 w = Wv[(size_t)k * (HDIM / 4)];
        const float *ip = in + k * FROWS + 8 * rh;
        float4 vA = *(const float4 *)ip;
        float4 vB = *(const float4 *)(ip + 4);
        accA[0] = f4fma(vA, w.x, accA[0]); accB[0] = f4fma(vB, w.x, accB[0]);
        accA[1] = f4fma(vA, w.y, accA[1]); accB[1] = f4fma(vB, w.y, accB[1]);
        accA[2] = f4fma(vA, w.z, accA[2]); accB[2] = f4fma(vB, w.z, accB[2]);
        accA[3] = f4fma(vA, w.w, accA[3]); accB[3] = f4fma(vB, w.w, accB[3]);
    }
    float4 b4 = ((const float4 *)bias)[cq];
    float bb[4] = {b4.x, b4.y, b4.z, b4.w};
#pragma unroll
    for (int j = 0; j < 4; ++j) {
        accA[j].x += bb[j]; accA[j].y += bb[j]; accA[j].z += bb[j]; accA[j].w += bb[j];
        accB[j].x += bb[j]; accB[j].y += bb[j]; accB[j].z += bb[j]; accB[j].w += bb[j];
    }
    const float inv = 1.f / (float)HDIM;
    float4 sA = f4add(f4add(accA[0], accA[1]), f4add(accA[2], accA[3]));
    float4 sB = f4add(f4add(accB[0], accB[1]), f4add(accB[2], accB[3]));
    redpair(sA, sB, redA, redB, tid);
    float4 mA = f4scale(sA, inv), mB = f4scale(sB, inv);
    float4 dA[4], dB[4];
    float4 qA = f4zero(), qB = f4zero();
#pragma unroll
    for (int j = 0; j < 4; ++j) {
        dA[j] = f4sub(accA[j], mA);
        dB[j] = f4sub(accB[j], mB);
        qA.x += dA[j].x * dA[j].x; qA.y += dA[j].y * dA[j].y;
        qA.z += dA[j].z * dA[j].z; qA.w += dA[j].w * dA[j].w;
        qB.x += dB[j].x * dB[j].x; qB.y += dB[j].y * dB[j].y;
        qB.z += dB[j].z * dB[j].z; qB.w += dB[j].w * dB[j].w;
    }
    redpair(qA, qB, redA, redB, tid);
    float4 rsA, rsB;
    rsA.x = 1.f / sqrtf(qA.x * inv + LN_EPS); rsA.y = 1.f / sqrtf(qA.y * inv + LN_EPS);
    rsA.z = 1.f / sqrtf(qA.z * inv + LN_EPS); rsA.w = 1.f / sqrtf(qA.w * inv + LN_EPS);
    rsB.x = 1.f / sqrtf(qB.x * inv + LN_EPS); rsB.y = 1.f / sqrtf(qB.y * inv + LN_EPS);
    rsB.z = 1.f / sqrtf(qB.z * inv + LN_EPS); rsB.w = 1.f / sqrtf(qB.w * inv + LN_EPS);
    float4 g4 = ((const float4 *)gam)[cq];
    float4 e4 = ((const float4 *)bet)[cq];
    float gg[4] = {g4.x, g4.y, g4.z, g4.w};
    float ee[4] = {e4.x, e4.y, e4.z, e4.w};
#pragma unroll
    for (int j = 0; j < 4; ++j) {
        float4 hA, hB;
        hA.x = fmaxf(fmaf(dA[j].x * rsA.x, gg[j], ee[j]), 0.f);
        hA.y = fmaxf(fmaf(dA[j].y * rsA.y, gg[j], ee[j]), 0.f);
        hA.z = fmaxf(fmaf(dA[j].z * rsA.z, gg[j], ee[j]), 0.f);
        hA.w = fmaxf(fmaf(dA[j].w * rsA.w, gg[j], ee[j]), 0.f);
        hB.x = fmaxf(fmaf(dB[j].x * rsB.x, gg[j], ee[j]), 0.f);
        hB.y = fmaxf(fmaf(dB[j].y * rsB.y, gg[j], ee[j]), 0.f);
        hB.z = fmaxf(fmaf(dB[j].z * rsB.z, gg[j], ee[j]), 0.f);
        hB.w = fmaxf(fmaf(dB[j].w * rsB.w, gg[j], ee[j]), 0.f);
        float *op = out + (4 * cq + j) * FROWS + 8 * rh;
        *(float4 *)op = hA;
        *(float4 *)(op + 4) = hB;
    }
    __syncthreads();
}

// ---------------- worker role: polls scan progress, evaluates fnet ------
__device__ void worker_role(const Params &P, int wid, WorkS &S) {
    const int tid = threadIdx.x;
    if (tid < VDIM) S.ord[tid] = P.top_order[tid];
    __syncthreads();
    if (tid < VDIM) S.invp[S.ord[tid]] = tid;
    __syncthreads();
    const int g = wid & (NGRP - 1);        // fixed row group
    const int r0 = g * FROWS;

    for (int tile = wid; tile < VDIM * NGRP; tile += NWORK) {
        const int t = tile >> 4;           // step
        if (t == VDIM - 1) continue;       // lf[127] replaced by score in loss
        if (tid == 0) {
            const int need = t + 1;
            for (int b = 0; b < SBPG; ++b) {
                // relaxed poll at coherence point -- NO buffer_inv, weights
                // stay cached in L2 for everyone on this XCD
                while (__hip_atomic_load(P.flag + (SBPG * g + b),
                                         __ATOMIC_RELAXED,
                                         __HIP_MEMORY_SCOPE_AGENT) < need)
                    __builtin_amdgcn_s_sleep(8);
            }
        }
        __syncthreads();
        for (int idx = tid; idx < VDIM * FROWS; idx += NT) {
            int k = idx >> 5, rr = idx & (FROWS - 1);
            int s = S.invp[k];
            S.Vt[idx] = (s <= t)
                ? __hip_atomic_load(&P.vs[(size_t)s * BATCH + r0 + rr],
                                    __ATOMIC_RELAXED, __HIP_MEMORY_SCOPE_AGENT)
                : 0.f;
        }
        __syncthreads();

        flayer512<VDIM>(S.Vt, P.f_w1, P.f_b1, P.f_g1, P.f_be1, S.A, S.redA, S.redB, tid);
        flayer512<HDIM>(S.A, P.f_w2, P.f_b2, P.f_g2, P.f_be2, S.A, S.redA, S.redB, tid);
        flayer512<HDIM>(S.A, P.f_w3, P.f_b3, P.f_g3, P.f_be3, S.A, S.redA, S.redB, tid);

        const int rh = tid >> 7, cq = tid & 127;
        float4 w4 = ((const float4 *)P.f_w4)[cq];
        float ww[4] = {w4.x, w4.y, w4.z, w4.w};
        float4 sA = f4zero(), sB = f4zero();
#pragma unroll
        for (int j = 0; j < 4; ++j) {
            const float *ap2 = S.A + (4 * cq + j) * FROWS + 8 * rh;
            float4 vA = *(const float4 *)ap2;
            float4 vB = *(const float4 *)(ap2 + 4);
            sA = f4fma(vA, ww[j], sA);
            sB = f4fma(vB, ww[j], sB);
        }
        redpair(sA, sB, S.redA, S.redB, tid);
        if (cq == 0) {
            float b4v = P.f_b4[0];
            float *dst = P.lf + (size_t)t * BATCH + r0 + 8 * rh;
            dst[0] = sA.x + b4v; dst[1] = sA.y + b4v;
            dst[2] = sA.z + b4v; dst[3] = sA.w + b4v;
            dst[4] = sB.x + b4v; dst[5] = sB.y + b4v;
            dst[6] = sB.z + b4v; dst[7] = sB.w + b4v;
        }
        __syncthreads();
    }
}

__global__ __launch_bounds__(NT) void gfn_main(Params P) {
    __shared__ SMem sm;
    if (blockIdx.x < NBLK) scan_role(P, blockIdx.x, sm.s);
    else                   worker_role(P, blockIdx.x - NBLK, sm.w);
}

// ---------------- loss ----------------
__global__ __launch_bounds__(NT) void gfn_loss(Params P) {
    __shared__ float H1[HDIM], H2[HDIM];
    __shared__ float red1[NWAVE];
    const int tid = threadIdx.x;
    const float inv = 1.f / (float)HDIM;

    float z = P.f_b1[tid];
    float m = block_reduce1(z, red1, tid) * inv;
    float d = z - m;
    float var = block_reduce1(d * d, red1, tid) * inv;
    float h = fmaxf(fmaf(d * (1.f / sqrtf(var + LN_EPS)), P.f_g1[tid], P.f_be1[tid]), 0.f);
    H1[tid] = h;
    __syncthreads();

    float acc = 0.f;
    for (int k = 0; k < HDIM; ++k) acc = fmaf(H1[k], P.f_w2[(size_t)k * HDIM + tid], acc);
    z = acc + P.f_b2[tid];
    m = block_reduce1(z, red1, tid) * inv;
    d = z - m;
    var = block_reduce1(d * d, red1, tid) * inv;
    h = fmaxf(fmaf(d * (1.f / sqrtf(var + LN_EPS)), P.f_g2[tid], P.f_be2[tid]), 0.f);
    H2[tid] = h;
    __syncthreads();

    acc = 0.f;
    for (int k = 0; k < HDIM; ++k) acc = fmaf(H2[k], P.f_w3[(size_t)k * HDIM + tid], acc);
    z = acc + P.f_b3[tid];
    m = block_reduce1(z, red1, tid) * inv;
    d = z - m;
    var = block_reduce1(d * d, red1, tid) * inv;
    h = fmaxf(fmaf(d * (1.f / sqrtf(var + LN_EPS)), P.f_g3[tid], P.f_be3[tid]), 0.f);
    float F0 = block_reduce1(h * P.f_w4[tid], red1, tid) + P.f_b4[0];

    const int b = tid;
    float lfp = F0;
    float s = 0.f;
    for (int t = 0; t < VDIM; ++t) {
        float lp = P.lp[(size_t)t * BATCH + b];
        float lfn = (t == VDIM - 1) ? P.score[b] : P.lf[(size_t)t * BATCH + b];
        float dd = lfp + lp - lfn;
        s = fmaf(dd, dd, s);
        lfp = lfn;
    }
    s *= (1.f / (float)VDIM);
    float total = block_reduce1(s, red1, tid) * (1.f / (float)BATCH);
    if (tid == 0) P.loss[0] = total;
}

extern "C" void kernel_launch(void *const *d_in, const int *in_sizes, int n_in,
                              void *d_out, int out_size, void *d_ws, size_t ws_size,
                              hipStream_t stream) {
    Params P;
    P.u     = (const float *)d_in[0];
    P.q_w1  = (const float *)d_in[1];
    P.q_b1  = (const float *)d_in[2];
    P.q_g1  = (const float *)d_in[3];
    P.q_be1 = (const float *)d_in[4];
    P.q_w2  = (const float *)d_in[5];
    P.q_b2  = (const float *)d_in[6];
    P.q_g2  = (const float *)d_in[7];
    P.q_be2 = (const float *)d_in[8];
    P.q_w3  = (const float *)d_in[9];
    P.q_b3  = (const float *)d_in[10];
    P.q_g3  = (const float *)d_in[11];
    P.q_be3 = (const float *)d_in[12];
    P.q_W   = (const float *)d_in[13];
    P.q_bias= (const float *)d_in[14];
    P.q_marg= (const float *)d_in[15];
    P.f_w1  = (const float *)d_in[16];
    P.f_b1  = (const float *)d_in[17];
    P.f_g1  = (const float *)d_in[18];
    P.f_be1 = (const float *)d_in[19];
    P.f_w2  = (const float *)d_in[20];
    P.f_b2  = (const float *)d_in[21];
    P.f_g2  = (const float *)d_in[22];
    P.f_be2 = (const float *)d_in[23];
    P.f_w3  = (const float *)d_in[24];
    P.f_b3  = (const float *)d_in[25];
    P.f_g3  = (const float *)d_in[26];
    P.f_be3 = (const float *)d_in[27];
    P.f_w4  = (const float *)d_in[28];
    P.f_b4  = (const float *)d_in[29];
    P.J     = (const float *)d_in[30];
    P.top_order = (const int *)d_in[31];
    P.pa_mask   = (const int *)d_in[32];

    float *ws = (float *)d_ws;
    P.V_out = (float *)d_out;
    P.loss  = (float *)d_out + (size_t)BATCH * VDIM;
    P.lp    = ws;                                       // [128][512]
    P.lf    = ws + (size_t)VDIM * BATCH;                // [128][512]
    P.score = ws + 2 * (size_t)VDIM * BATCH;            // [512]
    P.vs    = ws + 2 * (size_t)VDIM * BATCH + BATCH;    // [128][512]
    P.flag  = (int *)(ws + 3 * (size_t)VDIM * BATCH + BATCH);  // [128]

    hipMemsetAsync(P.flag, 0, NBLK * sizeof(int), stream);
    gfn_main<<<dim3(NBLK + NWORK), dim3(NT), 0, stream>>>(P);
    gfn_loss<<<dim3(1), dim3(NT), 0, stream>>>(P);
}

// Round 8
// 3820.956 us; speedup vs baseline: 1.2315x; 1.0924x over previous
//
#include <hip/hip_runtime.h>
#include <hip/hip_bf16.h>
#include <math.h>

#define VDIM 128
#define HDIM 512
#define BATCH 512
#define RPB 4                  // batch rows per scan block
#define NBLK (BATCH / RPB)     // 128 scan blocks
#define NWORK 128              // persistent fnet worker blocks
#define NT 512
#define NWAVE 8
#define LN_EPS 1e-5f
#define FROWS 32               // fnet rows per tile
#define NGRP (BATCH / FROWS)   // 16 row groups
#define SBPG (FROWS / RPB)     // 8 scan blocks per row group

// ---------- float4 helpers ----------
__device__ __forceinline__ float4 f4zero() { return make_float4(0.f, 0.f, 0.f, 0.f); }
__device__ __forceinline__ float4 f4add(float4 a, float4 b) {
    return make_float4(a.x + b.x, a.y + b.y, a.z + b.z, a.w + b.w);
}
__device__ __forceinline__ float4 f4fma(float4 a, float s, float4 c) {
    return make_float4(fmaf(a.x, s, c.x), fmaf(a.y, s, c.y),
                       fmaf(a.z, s, c.z), fmaf(a.w, s, c.w));
}
__device__ __forceinline__ float4 f4scale(float4 a, float s) {
    return make_float4(a.x * s, a.y * s, a.z * s, a.w * s);
}
__device__ __forceinline__ float4 f4sub(float4 a, float4 b) {
    return make_float4(a.x - b.x, a.y - b.y, a.z - b.z, a.w - b.w);
}
__device__ __forceinline__ float f4get(float4 v, int r) {
    return r == 0 ? v.x : r == 1 ? v.y : r == 2 ? v.z : v.w;
}

struct Params {
    const float *u;
    const float *q_w1, *q_b1, *q_g1, *q_be1;
    const float *q_w2, *q_b2, *q_g2, *q_be2;
    const float *q_w3, *q_b3, *q_g3, *q_be3;
    const float *q_W, *q_bias, *q_marg;
    const float *f_w1, *f_b1, *f_g1, *f_be1;
    const float *f_w2, *f_b2, *f_g2, *f_be2;
    const float *f_w3, *f_b3, *f_g3, *f_be3;
    const float *f_w4, *f_b4, *J;
    const int *top_order, *pa_mask;
    int *flag;
    float *V_out, *lp, *lf, *score, *vs, *loss;
};

// ---------------- shared-memory roles (union -> 83.4KB -> 1 block/CU) ----
struct ScanS {
    float4 VT[VDIM];           // V^T: [col] -> 4 rows
    float4 VPT[VDIM];          // permuted layer-1 input
    float4 ATa[HDIM];          // permuted activations (index st(c)=(c&3)*128+(c>>2))
    float4 ATb[HDIM];
    float4 part[4][4][128];    // [j][ks][cb]  32KB
    float4 redA[NWAVE], redB[NWAVE];
};
struct WorkS {
    float Vt[VDIM * FROWS];    // 16KB [k][32]
    float A[HDIM * FROWS];     // 64KB [c][32]
    int ord[VDIM], invp[VDIM];
    float4 redA[NWAVE], redB[NWAVE];
};
union SMem { ScanS s; WorkS w; };

// ---- block-wide f4 allreduce, ONE sync (caller rotates redA/redB) ------
__device__ __forceinline__ float4 allreduce4_1s(float4 v, float4 *red, int tid) {
#pragma unroll
    for (int off = 1; off < 64; off <<= 1) {
        v.x += __shfl_xor(v.x, off, 64);
        v.y += __shfl_xor(v.y, off, 64);
        v.z += __shfl_xor(v.z, off, 64);
        v.w += __shfl_xor(v.w, off, 64);
    }
    if ((tid & 63) == 0) red[tid >> 6] = v;
    __syncthreads();
    float4 s = red[0];
#pragma unroll
    for (int w = 1; w < NWAVE; ++w) s = f4add(s, red[w]);
    return s;   // NO trailing sync: next red-write is >=1 sync away by construction
}

__device__ __forceinline__ float block_reduce1(float v, float *red, int tid) {
#pragma unroll
    for (int off = 1; off < 64; off <<= 1) v += __shfl_xor(v, off, 64);
    if ((tid & 63) == 0) red[tid >> 6] = v;
    __syncthreads();
    float s = 0.f;
#pragma unroll
    for (int w = 0; w < NWAVE; ++w) s += red[w];
    __syncthreads();
    return s;
}

// ---- pair-wave reduce for worker (rows grouped 2 waves) ----------------
__device__ __forceinline__ void redpair(float4 &a, float4 &b,
                                        float4 *redA, float4 *redB, int tid) {
#pragma unroll
    for (int off = 1; off < 64; off <<= 1) {
        a.x += __shfl_xor(a.x, off, 64); a.y += __shfl_xor(a.y, off, 64);
        a.z += __shfl_xor(a.z, off, 64); a.w += __shfl_xor(a.w, off, 64);
        b.x += __shfl_xor(b.x, off, 64); b.y += __shfl_xor(b.y, off, 64);
        b.z += __shfl_xor(b.z, off, 64); b.w += __shfl_xor(b.w, off, 64);
    }
    int w = tid >> 6;
    if ((tid & 63) == 0) { redA[w] = a; redB[w] = b; }
    __syncthreads();
    int p = w ^ 1;
    a = f4add(redA[w], redA[p]);
    b = f4add(redB[w], redB[p]);
    __syncthreads();
}

// ---------------- scan GEMV+LN (4-way K-split, permuted activations) ----
template <int K>
__device__ __forceinline__ void gemv_ln_scan(const float4 *__restrict__ inA,
                                             const float *__restrict__ W,
                                             const float *__restrict__ bias,
                                             const float *__restrict__ gam,
                                             const float *__restrict__ bet,
                                             float4 *__restrict__ outA,
                                             ScanS &S, int tid, int ks, int cq,
                                             int myc) {
    constexpr int kc = K / 4;      // rows per ks-chunk
    constexpr int q4 = kc / 4;
    constexpr int seg = K / 4;     // permuted segment stride
    const float4 *Wp = (const float4 *)W + (size_t)(ks * kc) * (HDIM / 4) + cq;
    const float4 *ap = inA + ks * q4;
    float4 acc0 = f4zero(), acc1 = f4zero(), acc2 = f4zero(), acc3 = f4zero();
#pragma unroll 4
    for (int q = 0; q < q4; ++q) {
        float4 a0 = ap[q];                 // LDS b128 broadcast (k = ks*kc+4q+0)
        float4 a1 = ap[q + seg];           // k = ..+1
        float4 a2 = ap[q + 2 * seg];       // k = ..+2
        float4 a3 = ap[q + 3 * seg];       // k = ..+3
        float4 w0 = Wp[(size_t)(4 * q + 0) * (HDIM / 4)];   // 1KB/wave coalesced
        float4 w1 = Wp[(size_t)(4 * q + 1) * (HDIM / 4)];
        float4 w2 = Wp[(size_t)(4 * q + 2) * (HDIM / 4)];
        float4 w3 = Wp[(size_t)(4 * q + 3) * (HDIM / 4)];
        acc0 = f4fma(a0, w0.x, acc0); acc1 = f4fma(a0, w0.y, acc1);
        acc2 = f4fma(a0, w0.z, acc2); acc3 = f4fma(a0, w0.w, acc3);
        acc0 = f4fma(a1, w1.x, acc0); acc1 = f4fma(a1, w1.y, acc1);
        acc2 = f4fma(a1, w1.z, acc2); acc3 = f4fma(a1, w1.w, acc3);
        acc0 = f4fma(a2, w2.x, acc0); acc1 = f4fma(a2, w2.y, acc1);
        acc2 = f4fma(a2, w2.z, acc2); acc3 = f4fma(a2, w2.w, acc3);
        acc0 = f4fma(a3, w3.x, acc0); acc1 = f4fma(a3, w3.y, acc1);
        acc2 = f4fma(a3, w3.z, acc2); acc3 = f4fma(a3, w3.w, acc3);
    }
    // conflict-free partial writes (lane stride 16B per j)
    S.part[0][ks][cq] = acc0;
    S.part[1][ks][cq] = acc1;
    S.part[2][ks][cq] = acc2;
    S.part[3][ks][cq] = acc3;
    __syncthreads();
    // combine (conflict-free reads: per 2-wave group j fixed, cb contiguous)
    const int j = ks, cb = cq;     // same decomposition of tid
    float4 acc = f4add(f4add(S.part[j][0][cb], S.part[j][1][cb]),
                       f4add(S.part[j][2][cb], S.part[j][3][cb]));
    float bc = bias[myc];
    acc.x += bc; acc.y += bc; acc.z += bc; acc.w += bc;
    // two-pass LN over 512 columns
    const float inv = 1.f / (float)HDIM;
    float4 m4 = f4scale(allreduce4_1s(acc, S.redA, tid), inv);
    float4 d = f4sub(acc, m4);
    float4 sq = make_float4(d.x * d.x, d.y * d.y, d.z * d.z, d.w * d.w);
    float4 var = f4scale(allreduce4_1s(sq, S.redB, tid), inv);
    float4 rs;
    rs.x = 1.f / sqrtf(var.x + LN_EPS);
    rs.y = 1.f / sqrtf(var.y + LN_EPS);
    rs.z = 1.f / sqrtf(var.z + LN_EPS);
    rs.w = 1.f / sqrtf(var.w + LN_EPS);
    float gc = gam[myc], ec = bet[myc];
    float4 h;
    h.x = fmaxf(fmaf(d.x * rs.x, gc, ec), 0.f);
    h.y = fmaxf(fmaf(d.y * rs.y, gc, ec), 0.f);
    h.z = fmaxf(fmaf(d.z * rs.z, gc, ec), 0.f);
    h.w = fmaxf(fmaf(d.w * rs.w, gc, ec), 0.f);
    outA[tid] = h;                 // contiguous write = st(myc)
    __syncthreads();
}

// ---------------- scan role: qtrunk + sampling, publishes vs + flags ----
__device__ void scan_role(const Params &P, int bid, ScanS &S) {
    const int tid = threadIdx.x;
    const int ks = tid >> 7;
    const int cq = tid & 127;
    const int myc = 4 * cq + ks;
    const int row0 = bid * RPB;

    if (tid < VDIM) S.VT[tid] = f4zero();
    __syncthreads();

    for (int i = 0; i < VDIM; ++i) {
        const int node = P.top_order[i];

        float4 apv = f4zero();
        if (tid < VDIM) {
            float mk = (float)P.pa_mask[node * VDIM + tid];
            float4 vp = f4scale(S.VT[tid], mk);
            S.VPT[(tid & 3) * 32 + (tid >> 2)] = vp;   // permuted store
            apv = make_float4(fabsf(vp.x), fabsf(vp.y), fabsf(vp.z), fabsf(vp.w));
        }
        float4 asum = allreduce4_1s(apv, S.redB, tid);  // sync publishes VPT

        gemv_ln_scan<VDIM>(S.VPT, P.q_w1, P.q_b1, P.q_g1, P.q_be1, S.ATa, S, tid, ks, cq, myc);
        gemv_ln_scan<HDIM>(S.ATa, P.q_w2, P.q_b2, P.q_g2, P.q_be2, S.ATb, S, tid, ks, cq, myc);
        gemv_ln_scan<HDIM>(S.ATb, P.q_w3, P.q_b3, P.q_g3, P.q_be3, S.ATa, S, tid, ks, cq, myc);

        // head: x[r] = sum_c h3[r][c] * q_W[node][c]
        float wq = P.q_W[(size_t)node * HDIM + myc];
        float4 x4 = allreduce4_1s(f4scale(S.ATa[tid], wq), S.redA, tid);

        if (tid < RPB) {
            const int r = tid;
            float asr = f4get(asum, r);
            float xr = f4get(x4, r) + P.q_bias[node];
            float arg = (asr == 0.f) ? P.q_marg[node] : xr;
            float p = 1.f / (1.f + expf(-arg));
            float uv = P.u[i * BATCH + row0 + r];
            bool samp = uv < p;
            float v = samp ? 1.f : -1.f;
            ((float *)&S.VT[node])[r] = v;
            // publish at agent coherence point (no stale-L2 read possible)
            __hip_atomic_store(&P.vs[(size_t)i * BATCH + row0 + r], v,
                               __ATOMIC_RELAXED, __HIP_MEMORY_SCOPE_AGENT);
            P.lp[(size_t)i * BATCH + row0 + r] = samp ? logf(p) : log1pf(-p);
        }
        __syncthreads();
        if (tid == 0) {
            // release: orders the vs stores before the flag update
            __hip_atomic_store(P.flag + bid, i + 1,
                               __ATOMIC_RELEASE, __HIP_MEMORY_SCOPE_AGENT);
        }
    }

    // terminal score: V . J . V per row
    float4 inner = f4zero();
    if (tid < VDIM) {
#pragma unroll 4
        for (int ii = 0; ii < VDIM; ++ii)
            inner = f4fma(S.VT[ii], P.J[(size_t)ii * VDIM + tid], inner);
        float4 vc = S.VT[tid];
        inner = make_float4(inner.x * vc.x, inner.y * vc.y, inner.z * vc.z, inner.w * vc.w);
    }
    float4 sc4 = allreduce4_1s(inner, S.redA, tid);
    if (tid < RPB) P.score[row0 + tid] = f4get(sc4, tid);
    if (tid < VDIM) {
        float4 v = S.VT[tid];
        P.V_out[(size_t)(row0 + 0) * VDIM + tid] = v.x;
        P.V_out[(size_t)(row0 + 1) * VDIM + tid] = v.y;
        P.V_out[(size_t)(row0 + 2) * VDIM + tid] = v.z;
        P.V_out[(size_t)(row0 + 3) * VDIM + tid] = v.w;
    }
}

// ---------------- fnet layer, 512 threads, 32-row tile ------------------
template <int K>
__device__ __forceinline__ void flayer512(const float *__restrict__ in,
                                          const float *__restrict__ W,
                                          const float *__restrict__ bias,
                                          const float *__restrict__ gam,
                                          const float *__restrict__ bet,
                                          float *__restrict__ out,
                                          float4 *redA, float4 *redB, int tid) {
    const int rh = tid >> 7;       // row octet: rows 8rh..8rh+7
    const int cq = tid & 127;      // col f4 block
    const float4 *Wv = (const float4 *)W + cq;
    float4 accA[4], accB[4];
#pragma unroll
    for (int j = 0; j < 4; ++j) { accA[j] = f4zero(); accB[j] = f4zero(); }
#pragma unroll 4
    for (int k = 0; k < K; ++k) {
        float4 w = Wv[(size_t)k * (HDIM / 4)];
        const float *ip = in + k * FROWS + 8 * rh;
        float4 vA = *(const float4 *)ip;
        float4 vB = *(const float4 *)(ip + 4);
        accA[0] = f4fma(vA, w.x, accA[0]); accB[0] = f4fma(vB, w.x, accB[0]);
        accA[1] = f4fma(vA, w.y, accA[1]); accB[1] = f4fma(vB, w.y, accB[1]);
        accA[2] = f4fma(vA, w.z, accA[2]); accB[2] = f4fma(vB, w.z, accB[2]);
        accA[3] = f4fma(vA, w.w, accA[3]); accB[3] = f4fma(vB, w.w, accB[3]);
    }
    float4 b4 = ((const float4 *)bias)[cq];
    float bb[4] = {b4.x, b4.y, b4.z, b4.w};
#pragma unroll
    for (int j = 0; j < 4; ++j) {
        accA[j].x += bb[j]; accA[j].y += bb[j]; accA[j].z += bb[j]; accA[j].w += bb[j];
        accB[j].x += bb[j]; accB[j].y += bb[j]; accB[j].z += bb[j]; accB[j].w += bb[j];
    }
    const float inv = 1.f / (float)HDIM;
    float4 sA = f4add(f4add(accA[0], accA[1]), f4add(accA[2], accA[3]));
    float4 sB = f4add(f4add(accB[0], accB[1]), f4add(accB[2], accB[3]));
    redpair(sA, sB, redA, redB, tid);
    float4 mA = f4scale(sA, inv), mB = f4scale(sB, inv);
    float4 dA[4], dB[4];
    float4 qA = f4zero(), qB = f4zero();
#pragma unroll
    for (int j = 0; j < 4; ++j) {
        dA[j] = f4sub(accA[j], mA);
        dB[j] = f4sub(accB[j], mB);
        qA.x += dA[j].x * dA[j].x; qA.y += dA[j].y * dA[j].y;
        qA.z += dA[j].z * dA[j].z; qA.w += dA[j].w * dA[j].w;
        qB.x += dB[j].x * dB[j].x; qB.y += dB[j].y * dB[j].y;
        qB.z += dB[j].z * dB[j].z; qB.w += dB[j].w * dB[j].w;
    }
    redpair(qA, qB, redA, redB, tid);
    float4 rsA, rsB;
    rsA.x = 1.f / sqrtf(qA.x * inv + LN_EPS); rsA.y = 1.f / sqrtf(qA.y * inv + LN_EPS);
    rsA.z = 1.f / sqrtf(qA.z * inv + LN_EPS); rsA.w = 1.f / sqrtf(qA.w * inv + LN_EPS);
    rsB.x = 1.f / sqrtf(qB.x * inv + LN_EPS); rsB.y = 1.f / sqrtf(qB.y * inv + LN_EPS);
    rsB.z = 1.f / sqrtf(qB.z * inv + LN_EPS); rsB.w = 1.f / sqrtf(qB.w * inv + LN_EPS);
    float4 g4 = ((const float4 *)gam)[cq];
    float4 e4 = ((const float4 *)bet)[cq];
    float gg[4] = {g4.x, g4.y, g4.z, g4.w};
    float ee[4] = {e4.x, e4.y, e4.z, e4.w};
#pragma unroll
    for (int j = 0; j < 4; ++j) {
        float4 hA, hB;
        hA.x = fmaxf(fmaf(dA[j].x * rsA.x, gg[j], ee[j]), 0.f);
        hA.y = fmaxf(fmaf(dA[j].y * rsA.y, gg[j], ee[j]), 0.f);
        hA.z = fmaxf(fmaf(dA[j].z * rsA.z, gg[j], ee[j]), 0.f);
        hA.w = fmaxf(fmaf(dA[j].w * rsA.w, gg[j], ee[j]), 0.f);
        hB.x = fmaxf(fmaf(dB[j].x * rsB.x, gg[j], ee[j]), 0.f);
        hB.y = fmaxf(fmaf(dB[j].y * rsB.y, gg[j], ee[j]), 0.f);
        hB.z = fmaxf(fmaf(dB[j].z * rsB.z, gg[j], ee[j]), 0.f);
        hB.w = fmaxf(fmaf(dB[j].w * rsB.w, gg[j], ee[j]), 0.f);
        float *op = out + (4 * cq + j) * FROWS + 8 * rh;
        *(float4 *)op = hA;
        *(float4 *)(op + 4) = hB;
    }
    __syncthreads();
}

// ---------------- worker role: polls scan progress, evaluates fnet ------
__device__ void worker_role(const Params &P, int wid, WorkS &S) {
    const int tid = threadIdx.x;
    if (tid < VDIM) S.ord[tid] = P.top_order[tid];
    __syncthreads();
    if (tid < VDIM) S.invp[S.ord[tid]] = tid;
    __syncthreads();
    const int g = wid & (NGRP - 1);        // fixed row group
    const int r0 = g * FROWS;

    for (int tile = wid; tile < VDIM * NGRP; tile += NWORK) {
        const int t = tile >> 4;           // step
        if (t == VDIM - 1) continue;       // lf[127] replaced by score in loss
        if (tid < SBPG) {
            const int need = t + 1;
            // relaxed poll at coherence point (8 lanes, one flag each)
            while (__hip_atomic_load(P.flag + (SBPG * g + tid),
                                     __ATOMIC_RELAXED,
                                     __HIP_MEMORY_SCOPE_AGENT) < need)
                __builtin_amdgcn_s_sleep(4);
        }
        __syncthreads();
        for (int idx = tid; idx < VDIM * FROWS; idx += NT) {
            int k = idx >> 5, rr = idx & (FROWS - 1);
            int s = S.invp[k];
            S.Vt[idx] = (s <= t)
                ? __hip_atomic_load(&P.vs[(size_t)s * BATCH + r0 + rr],
                                    __ATOMIC_RELAXED, __HIP_MEMORY_SCOPE_AGENT)
                : 0.f;
        }
        __syncthreads();

        flayer512<VDIM>(S.Vt, P.f_w1, P.f_b1, P.f_g1, P.f_be1, S.A, S.redA, S.redB, tid);
        flayer512<HDIM>(S.A, P.f_w2, P.f_b2, P.f_g2, P.f_be2, S.A, S.redA, S.redB, tid);
        flayer512<HDIM>(S.A, P.f_w3, P.f_b3, P.f_g3, P.f_be3, S.A, S.redA, S.redB, tid);

        const int rh = tid >> 7, cq = tid & 127;
        float4 w4 = ((const float4 *)P.f_w4)[cq];
        float ww[4] = {w4.x, w4.y, w4.z, w4.w};
        float4 sA = f4zero(), sB = f4zero();
#pragma unroll
        for (int j = 0; j < 4; ++j) {
            const float *ap2 = S.A + (4 * cq + j) * FROWS + 8 * rh;
            float4 vA = *(const float4 *)ap2;
            float4 vB = *(const float4 *)(ap2 + 4);
            sA = f4fma(vA, ww[j], sA);
            sB = f4fma(vB, ww[j], sB);
        }
        redpair(sA, sB, S.redA, S.redB, tid);
        if (cq == 0) {
            float b4v = P.f_b4[0];
            float *dst = P.lf + (size_t)t * BATCH + r0 + 8 * rh;
            dst[0] = sA.x + b4v; dst[1] = sA.y + b4v;
            dst[2] = sA.z + b4v; dst[3] = sA.w + b4v;
            dst[4] = sB.x + b4v; dst[5] = sB.y + b4v;
            dst[6] = sB.z + b4v; dst[7] = sB.w + b4v;
        }
        __syncthreads();
    }
}

// XCD-partitioned role assignment: blockIdx round-robins across the 8 XCDs
// (perf heuristic only). Scan blocks -> XCDs 0-3 (q-weights pinned in those
// L2s, 2.5MB each); workers -> XCDs 4-7 (f-weights, 2.25MB each). Both fit
// 4MB L2 -> no thrash. 1 block/CU (83.4KB LDS) => all 256 blocks co-resident
// whatever the real mapping is, so the flag protocol cannot deadlock.
__global__ __launch_bounds__(NT) void gfn_main(Params P) {
    __shared__ SMem sm;
    const int xcd = blockIdx.x & 7;
    const int grp = blockIdx.x >> 3;       // 0..31
    if (xcd < 4) scan_role(P, grp * 4 + xcd, sm.s);
    else         worker_role(P, grp * 4 + (xcd - 4), sm.w);
}

// ---------------- loss ----------------
__global__ __launch_bounds__(NT) void gfn_loss(Params P) {
    __shared__ float H1[HDIM], H2[HDIM];
    __shared__ float red1[NWAVE];
    const int tid = threadIdx.x;
    const float inv = 1.f / (float)HDIM;

    float z = P.f_b1[tid];
    float m = block_reduce1(z, red1, tid) * inv;
    float d = z - m;
    float var = block_reduce1(d * d, red1, tid) * inv;
    float h = fmaxf(fmaf(d * (1.f / sqrtf(var + LN_EPS)), P.f_g1[tid], P.f_be1[tid]), 0.f);
    H1[tid] = h;
    __syncthreads();

    float acc = 0.f;
    for (int k = 0; k < HDIM; ++k) acc = fmaf(H1[k], P.f_w2[(size_t)k * HDIM + tid], acc);
    z = acc + P.f_b2[tid];
    m = block_reduce1(z, red1, tid) * inv;
    d = z - m;
    var = block_reduce1(d * d, red1, tid) * inv;
    h = fmaxf(fmaf(d * (1.f / sqrtf(var + LN_EPS)), P.f_g2[tid], P.f_be2[tid]), 0.f);
    H2[tid] = h;
    __syncthreads();

    acc = 0.f;
    for (int k = 0; k < HDIM; ++k) acc = fmaf(H2[k], P.f_w3[(size_t)k * HDIM + tid], acc);
    z = acc + P.f_b3[tid];
    m = block_reduce1(z, red1, tid) * inv;
    d = z - m;
    var = block_reduce1(d * d, red1, tid) * inv;
    h = fmaxf(fmaf(d * (1.f / sqrtf(var + LN_EPS)), P.f_g3[tid], P.f_be3[tid]), 0.f);
    float F0 = block_reduce1(h * P.f_w4[tid], red1, tid) + P.f_b4[0];

    const int b = tid;
    float lfp = F0;
    float s = 0.f;
    for (int t = 0; t < VDIM; ++t) {
        float lp = P.lp[(size_t)t * BATCH + b];
        float lfn = (t == VDIM - 1) ? P.score[b] : P.lf[(size_t)t * BATCH + b];
        float dd = lfp + lp - lfn;
        s = fmaf(dd, dd, s);
        lfp = lfn;
    }
    s *= (1.f / (float)VDIM);
    float total = block_reduce1(s, red1, tid) * (1.f / (float)BATCH);
    if (tid == 0) P.loss[0] = total;
}

extern "C" void kernel_launch(void *const *d_in, const int *in_sizes, int n_in,
                              void *d_out, int out_size, void *d_ws, size_t ws_size,
                              hipStream_t stream) {
    Params P;
    P.u     = (const float *)d_in[0];
    P.q_w1  = (const float *)d_in[1];
    P.q_b1  = (const float *)d_in[2];
    P.q_g1  = (const float *)d_in[3];
    P.q_be1 = (const float *)d_in[4];
    P.q_w2  = (const float *)d_in[5];
    P.q_b2  = (const float *)d_in[6];
    P.q_g2  = (const float *)d_in[7];
    P.q_be2 = (const float *)d_in[8];
    P.q_w3  = (const float *)d_in[9];
    P.q_b3  = (const float *)d_in[10];
    P.q_g3  = (const float *)d_in[11];
    P.q_be3 = (const float *)d_in[12];
    P.q_W   = (const float *)d_in[13];
    P.q_bias= (const float *)d_in[14];
    P.q_marg= (const float *)d_in[15];
    P.f_w1  = (const float *)d_in[16];
    P.f_b1  = (const float *)d_in[17];
    P.f_g1  = (const float *)d_in[18];
    P.f_be1 = (const float *)d_in[19];
    P.f_w2  = (const float *)d_in[20];
    P.f_b2  = (const float *)d_in[21];
    P.f_g2  = (const float *)d_in[22];
    P.f_be2 = (const float *)d_in[23];
    P.f_w3  = (const float *)d_in[24];
    P.f_b3  = (const float *)d_in[25];
    P.f_g3  = (const float *)d_in[26];
    P.f_be3 = (const float *)d_in[27];
    P.f_w4  = (const float *)d_in[28];
    P.f_b4  = (const float *)d_in[29];
    P.J     = (const float *)d_in[30];
    P.top_order = (const int *)d_in[31];
    P.pa_mask   = (const int *)d_in[32];

    float *ws = (float *)d_ws;
    P.V_out = (float *)d_out;
    P.loss  = (float *)d_out + (size_t)BATCH * VDIM;
    P.lp    = ws;                                       // [128][512]
    P.lf    = ws + (size_t)VDIM * BATCH;                // [128][512]
    P.score = ws + 2 * (size_t)VDIM * BATCH;            // [512]
    P.vs    = ws + 2 * (size_t)VDIM * BATCH + BATCH;    // [128][512]
    P.flag  = (int *)(ws + 3 * (size_t)VDIM * BATCH + BATCH);  // [128]

    hipMemsetAsync(P.flag, 0, NBLK * sizeof(int), stream);
    gfn_main<<<dim3(NBLK + NWORK), dim3(NT), 0, stream>>>(P);
    gfn_loss<<<dim3(1), dim3(NT), 0, stream>>>(P);
}